// Round 10
// baseline (444.963 us; speedup 1.0000x reference)
//
#include <hip/hip_runtime.h>
#include <hip/hip_bf16.h>
#include <math.h>

#define B_TOT 512
#define SEQ   179
#define EMB   256
#define HEADS 8
#define HD    32
#define LIN   720
#define EPSV  1e-5f

typedef __attribute__((ext_vector_type(8))) short bf16x8;
typedef __attribute__((ext_vector_type(4))) float f32x4;

__device__ __forceinline__ short f2bf(float f) {          // RNE f32->bf16 bits
    unsigned u = __float_as_uint(f);
    return (short)((u + 0x7fff + ((u >> 16) & 1)) >> 16);
}
__device__ __forceinline__ unsigned cvt_pk_bf16(float lo, float hi) {
    unsigned r;
    asm("v_cvt_pk_bf16_f32 %0, %1, %2" : "=v"(r) : "v"(lo), "v"(hi));
    return r;
}

// ---------------------------------------------------------------- PE table
__global__ void pe_kernel(float* __restrict__ pe) {
    int idx = blockIdx.x * 256 + threadIdx.x;
    if (idx >= SEQ * EMB) return;
    int s = idx / EMB, e = idx % EMB;
    int i = e >> 1;
    float dv  = expf((float)(2 * i) * (-9.210340371976184f / (float)EMB));
    float ang = (float)s * dv * ((float)EMB / (float)SEQ);
    pe[idx] = (e & 1) ? cosf(ang) : sinf(ang);
}

// ------------------------------------- f32 -> bf16 convert, 6 weights at once
__global__ void cvt6_kernel(const float* __restrict__ s0, const float* __restrict__ s1,
                            const float* __restrict__ s2, const float* __restrict__ s3,
                            const float* __restrict__ s4, const float* __restrict__ s5,
                            __hip_bfloat16* __restrict__ dst, int n) {
    int w = blockIdx.y;
    const float* src = (w == 0) ? s0 : (w == 1) ? s1 : (w == 2) ? s2
                     : (w == 3) ? s3 : (w == 4) ? s4 : s5;
    __hip_bfloat16* d = dst + (size_t)w * n;
    int i = (blockIdx.x * 256 + threadIdx.x) * 4;
    if (i < n) {
        float4 v = *reinterpret_cast<const float4*>(&src[i]);
        d[i + 0] = __float2bfloat16(v.x);
        d[i + 1] = __float2bfloat16(v.y);
        d[i + 2] = __float2bfloat16(v.z);
        d[i + 3] = __float2bfloat16(v.w);
    }
}

// ------------------------ conv(stride4,K8) + BN + ReLU + PE -> bf16 X
__global__ __launch_bounds__(256) void embed_kernel(
    const float* __restrict__ x, const float* __restrict__ cw,
    const float* __restrict__ cb, const float* __restrict__ g,
    const float* __restrict__ bb, const float* __restrict__ mean,
    const float* __restrict__ var, const float* __restrict__ pe,
    __hip_bfloat16* __restrict__ Xb)
{
    int bs = blockIdx.x;
    int b  = bs / SEQ, s = bs % SEQ;
    int e  = threadIdx.x;
    __shared__ float xin[8];
    if (threadIdx.x < 8) xin[threadIdx.x] = x[(size_t)b * LIN + s * 4 + threadIdx.x];
    __syncthreads();
    float acc = cb[e];
#pragma unroll
    for (int j = 0; j < 8; ++j) acc += xin[j] * cw[e * 8 + j];
    acc = (acc - mean[e]) * (g[e] * rsqrtf(var[e] + EPSV)) + bb[e];
    acc = fmaxf(acc, 0.f);
    Xb[(size_t)bs * EMB + e] = __float2bfloat16(acc + pe[s * EMB + e]);
}

// ---------------- MFMA bf16 GEMM: C[m,n] = sum_k A[m,k] * W[n,k], C in bf16
__global__ __launch_bounds__(256) void gemm_qkv_mfma(
    const __hip_bfloat16* __restrict__ A,    // [Mpad][256]
    const __hip_bfloat16* __restrict__ Wset, // [3][256][256]
    __hip_bfloat16* __restrict__ Q, __hip_bfloat16* __restrict__ K,
    __hip_bfloat16* __restrict__ V, int M)
{
    int by = blockIdx.y;                       // 0..5
    int wsel = by >> 1;
    const __hip_bfloat16* W = Wset + (size_t)wsel * EMB * EMB;
    __hip_bfloat16* C = (wsel == 0) ? Q : (wsel == 1 ? K : V);
    int nbase = (by & 1) * 128;
    int mbase = blockIdx.x * 128;

    __shared__ __hip_bfloat16 As[128][64];
    __shared__ __hip_bfloat16 Bs[128][64];

    int tid  = threadIdx.x;
    int wave = tid >> 6, lane = tid & 63;
    int wr = wave >> 1, wc = wave & 1;

    int r0   = tid >> 3;
    int srcs = (tid & 7) ^ (r0 & 7);
    const __hip_bfloat16* gA = A + (size_t)(mbase + r0) * EMB + srcs * 8;
    const __hip_bfloat16* gB = W + (size_t)(nbase + r0) * EMB + srcs * 8;

    f32x4 acc[4][4];
#pragma unroll
    for (int i = 0; i < 4; ++i)
#pragma unroll
        for (int j = 0; j < 4; ++j) acc[i][j] = (f32x4){0.f, 0.f, 0.f, 0.f};

    for (int kt = 0; kt < EMB; kt += 64) {
        if (kt) __syncthreads();
#pragma unroll
        for (int i = 0; i < 4; ++i) {
            __hip_bfloat16* l = &As[0][0] + i * 2048 + tid * 8;
            __builtin_amdgcn_global_load_lds(
                (const __attribute__((address_space(1))) void*)(gA + (size_t)i * 32 * EMB + kt),
                (__attribute__((address_space(3))) void*)l, 16, 0, 0);
        }
#pragma unroll
        for (int i = 0; i < 4; ++i) {
            __hip_bfloat16* l = &Bs[0][0] + i * 2048 + tid * 8;
            __builtin_amdgcn_global_load_lds(
                (const __attribute__((address_space(1))) void*)(gB + (size_t)i * 32 * EMB + kt),
                (__attribute__((address_space(3))) void*)l, 16, 0, 0);
        }
        asm volatile("s_waitcnt vmcnt(0)" ::: "memory");
        __syncthreads();

#pragma unroll
        for (int kk = 0; kk < 2; ++kk) {
            bf16x8 af[4], bfr[4];
            int sg = kk * 4 + (lane >> 4);
#pragma unroll
            for (int mi = 0; mi < 4; ++mi) {
                int row = wr * 64 + mi * 16 + (lane & 15);
                int sl  = sg ^ (row & 7);
                af[mi] = *reinterpret_cast<const bf16x8*>(&As[row][sl * 8]);
            }
#pragma unroll
            for (int ni = 0; ni < 4; ++ni) {
                int row = wc * 64 + ni * 16 + (lane & 15);
                int sl  = sg ^ (row & 7);
                bfr[ni] = *reinterpret_cast<const bf16x8*>(&Bs[row][sl * 8]);
            }
#pragma unroll
            for (int mi = 0; mi < 4; ++mi)
#pragma unroll
                for (int ni = 0; ni < 4; ++ni)
                    acc[mi][ni] = __builtin_amdgcn_mfma_f32_16x16x32_bf16(
                        af[mi], bfr[ni], acc[mi][ni], 0, 0, 0);
        }
    }

    int rg = lane >> 4, cli = lane & 15;
#pragma unroll
    for (int mi = 0; mi < 4; ++mi)
#pragma unroll
        for (int j = 0; j < 4; ++j) {
            int m = mbase + wr * 64 + mi * 16 + rg * 4 + j;
            if (m < M) {
#pragma unroll
                for (int ni = 0; ni < 4; ++ni)
                    C[(size_t)m * EMB + nbase + wc * 64 + ni * 16 + cli] =
                        __float2bfloat16(acc[mi][ni][j]);
            }
        }
}

// ---------------- MFMA flash attention v3: swapped QK^T (q lane-local),
// cvt_pk packed P writes, scalar lrow. Block per (b,h), 4 waves x 48 q-rows.
__global__ __launch_bounds__(256) void attn_mfma_kernel(
    const __hip_bfloat16* __restrict__ Qb, const __hip_bfloat16* __restrict__ Kb,
    const __hip_bfloat16* __restrict__ Vb, __hip_bfloat16* __restrict__ O)
{
    int bh = blockIdx.x;
    int b = bh >> 3, h = bh & 7;
    const size_t base = (size_t)b * SEQ * EMB + (size_t)h * HD;

    // K2: row = t>>1, slot = (t&1)*4 + d/8, phys = slot^(row&7)
    __shared__ short K2[96][64];          // 12288 B
    // Vt: row = d, slot = t>>3, phys = slot^(d&7)
    __shared__ short Vt[32][256];         // 16384 B
    // P2: per wave, row = q(16), t in [0,96), stride 104 (13x16B -> ~2-way)
    __shared__ short P2[4][16][104];      // 13312 B

    int tid  = threadIdx.x;
    int wave = tid >> 6, lane = tid & 63;
    int cl = lane & 15, rg = lane >> 4;

    // ---- stage K (swizzled b128) + V transposed (rotated scalar scatter)
    for (int u = tid; u < 192 * 4; u += 256) {
        int t = u >> 2, d0 = (u & 3) << 3;
        uint4 kv = make_uint4(0, 0, 0, 0), vv = make_uint4(0, 0, 0, 0);
        if (t < SEQ) {
            kv = *reinterpret_cast<const uint4*>(&Kb[base + (size_t)t * EMB + d0]);
            vv = *reinterpret_cast<const uint4*>(&Vb[base + (size_t)t * EMB + d0]);
        }
        int krow = t >> 1;
        int kphy = (((t & 1) * 4 + (d0 >> 3)) ^ (krow & 7));
        *reinterpret_cast<uint4*>(&K2[krow][kphy * 8]) = kv;

        const unsigned short* pv = reinterpret_cast<const unsigned short*>(&vv);
        int slot = t >> 3;
        int rot  = (u & 3) * 2;
#pragma unroll
        for (int k = 0; k < 8; ++k) {
            int i = (k + rot) & 7;          // d&7 varies across lanes per instr
            int d = d0 + i;
            Vt[d][(slot ^ i) * 8 + (t & 7)] = (short)pv[i];
        }
    }
    __syncthreads();

    // scale/SEQ * log2(e), for exp2
    const float csw2 = (0.0625f / (float)SEQ) * 1.4426950408889634f;

    for (int qt = 0; qt < 3; ++qt) {
        int qbase = wave * 48 + qt * 16;

        // Q fragment (B operand): col = cl -> q = qbase+cl, k(d) = rg*8..+7
        bf16x8 aq = {};
        int sq = qbase + cl;
        if (sq < SEQ)
            aq = *reinterpret_cast<const bf16x8*>(&Qb[base + (size_t)sq * EMB + rg * 8]);
        float sf = (float)sq;

        f32x4 o0 = {0.f, 0.f, 0.f, 0.f}, o1 = {0.f, 0.f, 0.f, 0.f};
        float lrow = 0.f;                 // row-sum for q = cl (partial over rg)

        for (int hh = 0; hh < 2; ++hh) {
            // ---- K^T Q: swapped operands -> C[row=t_loc][col=q_loc]
            // per lane: q = cl (fixed), t = tile*16 + rg*4 + j
            f32x4 st[6];
#pragma unroll
            for (int tl = 0; tl < 6; ++tl) {
                int t   = (hh * 6 + tl) * 16 + cl;   // A-frag row index uses cl
                int kr  = t >> 1;
                int kph = (((t & 1) * 4 + rg) ^ (kr & 7));
                bf16x8 kf = *reinterpret_cast<const bf16x8*>(&K2[kr][kph * 8]);
                st[tl] = __builtin_amdgcn_mfma_f32_16x16x32_bf16(
                    kf, aq, (f32x4){0.f, 0.f, 0.f, 0.f}, 0, 0, 0);
            }

            // ---- fused weight+exp+sum + packed P write (4 consecutive t/lane)
#pragma unroll
            for (int tl = 0; tl < 6; ++tl) {
                int tb = hh * 96 + tl * 16 + rg * 4;
                float d0 = sf - (float)tb;
                float p[4];
#pragma unroll
                for (int j = 0; j < 4; ++j)
                    p[j] = exp2f(st[tl][j] * (fabsf(d0 - (float)j) * csw2));
                if (hh == 1 && tl == 5) {            // only tile containing t>=SEQ
#pragma unroll
                    for (int j = 0; j < 4; ++j)
                        if (tb + j >= SEQ) p[j] = 0.f;
                }
                lrow += (p[0] + p[1]) + (p[2] + p[3]);
                uint2 pk;
                pk.x = cvt_pk_bf16(p[0], p[1]);
                pk.y = cvt_pk_bf16(p[2], p[3]);
                *reinterpret_cast<uint2*>(&P2[wave][cl][tl * 16 + rg * 4]) = pk;
            }
            asm volatile("s_waitcnt lgkmcnt(0)" ::: "memory"); // wave-local wr->rd

            // ---- PV for this half: 3 t-chunks of 32
#pragma unroll
            for (int tcl = 0; tcl < 3; ++tcl) {
                bf16x8 pa = *reinterpret_cast<const bf16x8*>(&P2[wave][cl][tcl * 32 + rg * 8]);
                int vsl = ((hh * 3 + tcl) * 4 + rg);
                int vp0 = (vsl ^ (cl & 7));
                bf16x8 b0 = *reinterpret_cast<const bf16x8*>(&Vt[cl][vp0 * 8]);
                bf16x8 b1 = *reinterpret_cast<const bf16x8*>(&Vt[cl + 16][vp0 * 8]);
                o0 = __builtin_amdgcn_mfma_f32_16x16x32_bf16(pa, b0, o0, 0, 0, 0);
                o1 = __builtin_amdgcn_mfma_f32_16x16x32_bf16(pa, b1, o1, 0, 0, 0);
            }
            asm volatile("s_waitcnt lgkmcnt(0)" ::: "memory"); // reads done before P reuse
        }

        // ---- full row sum for q=cl: reduce across the 4 rg-groups
        lrow += __shfl_xor(lrow, 16);
        lrow += __shfl_xor(lrow, 32);

        // ---- store bf16; row q = qbase + rg*4 + j needs lrow from lane rg*4+j
#pragma unroll
        for (int j = 0; j < 4; ++j) {
            int s = qbase + rg * 4 + j;
            if (s < SEQ) {
                float rl = 1.0f / __shfl(lrow, rg * 4 + j);
                __hip_bfloat16* op = &O[base + (size_t)s * EMB];
                op[cl]      = __float2bfloat16(o0[j] * rl);
                op[16 + cl] = __float2bfloat16(o1[j] * rl);
            }
        }
    }
}

// ---------------- row LayerNorm + PE: wave-per-row, 4 rows/block, bf16 io
__global__ __launch_bounds__(256) void ln_pe4_kernel(
    const __hip_bfloat16* __restrict__ X, const float* __restrict__ g,
    const float* __restrict__ bb, const float* __restrict__ pe,
    __hip_bfloat16* __restrict__ Xb, int M)
{
    int r = blockIdx.x * 4 + (threadIdx.x >> 6);
    if (r >= M) return;
    int lane = threadIdx.x & 63;
    int s = r % SEQ;
    int c0 = lane * 4;

    uint2 raw = *reinterpret_cast<const uint2*>(&X[(size_t)r * EMB + c0]);
    float v[4];
    v[0] = __uint_as_float((raw.x & 0xffffu) << 16);
    v[1] = __uint_as_float(raw.x & 0xffff0000u);
    v[2] = __uint_as_float((raw.y & 0xffffu) << 16);
    v[3] = __uint_as_float(raw.y & 0xffff0000u);

    float sum = v[0] + v[1] + v[2] + v[3];
    float sq  = v[0]*v[0] + v[1]*v[1] + v[2]*v[2] + v[3]*v[3];
#pragma unroll
    for (int off = 32; off > 0; off >>= 1) {
        sum += __shfl_xor(sum, off);
        sq  += __shfl_xor(sq,  off);
    }
    float mu  = sum * (1.0f / EMB);
    float var = sq * (1.0f / EMB) - mu * mu;
    float is  = rsqrtf(var + EPSV);

    float4 gv = *reinterpret_cast<const float4*>(&g[c0]);
    float4 bv = *reinterpret_cast<const float4*>(&bb[c0]);
    float4 pv = *reinterpret_cast<const float4*>(&pe[s * EMB + c0]);
    float y0 = (v[0] - mu) * is * gv.x + bv.x + pv.x;
    float y1 = (v[1] - mu) * is * gv.y + bv.y + pv.y;
    float y2 = (v[2] - mu) * is * gv.z + bv.z + pv.z;
    float y3 = (v[3] - mu) * is * gv.w + bv.w + pv.w;

    uint2 o;
    o.x = (unsigned short)f2bf(y0) | ((unsigned)(unsigned short)f2bf(y1) << 16);
    o.y = (unsigned short)f2bf(y2) | ((unsigned)(unsigned short)f2bf(y3) << 16);
    *reinterpret_cast<uint2*>(&Xb[(size_t)r * EMB + c0]) = o;
}

// ------- fused: LN(lnA2) -> LN(ln2) -> mean-pool over SEQ -> FC[10]
__global__ __launch_bounds__(256) void lnfc_kernel(
    const __hip_bfloat16* __restrict__ X,
    const float* __restrict__ g1, const float* __restrict__ b1,
    const float* __restrict__ g2, const float* __restrict__ b2,
    const float* __restrict__ ow, const float* __restrict__ ob,
    float* __restrict__ out)
{
    int b    = blockIdx.x;
    int tid  = threadIdx.x;
    int wave = tid >> 6, lane = tid & 63;

    float g1v[4], b1v[4], g2v[4], b2v[4], pooled[4];
#pragma unroll
    for (int j = 0; j < 4; ++j) {
        int c = lane + 64 * j;
        g1v[j] = g1[c]; b1v[j] = b1[c];
        g2v[j] = g2[c]; b2v[j] = b2[c];
        pooled[j] = 0.f;
    }

    for (int s = wave; s < SEQ; s += 4) {
        const __hip_bfloat16* row = &X[((size_t)b * SEQ + s) * EMB];
        float v[4];
#pragma unroll
        for (int j = 0; j < 4; ++j) v[j] = __bfloat162float(row[lane + 64 * j]);

        float sum = v[0] + v[1] + v[2] + v[3];
        float sq  = v[0]*v[0] + v[1]*v[1] + v[2]*v[2] + v[3]*v[3];
#pragma unroll
        for (int off = 32; off > 0; off >>= 1) {
            sum += __shfl_xor(sum, off);
            sq  += __shfl_xor(sq,  off);
        }
        float mu  = sum * (1.0f / EMB);
        float var = sq * (1.0f / EMB) - mu * mu;
        float is  = rsqrtf(var + EPSV);
        float y[4];
#pragma unroll
        for (int j = 0; j < 4; ++j) y[j] = (v[j] - mu) * is * g1v[j] + b1v[j];

        sum = y[0] + y[1] + y[2] + y[3];
        sq  = y[0]*y[0] + y[1]*y[1] + y[2]*y[2] + y[3]*y[3];
#pragma unroll
        for (int off = 32; off > 0; off >>= 1) {
            sum += __shfl_xor(sum, off);
            sq  += __shfl_xor(sq,  off);
        }
        mu  = sum * (1.0f / EMB);
        var = sq * (1.0f / EMB) - mu * mu;
        is  = rsqrtf(var + EPSV);
#pragma unroll
        for (int j = 0; j < 4; ++j) pooled[j] += (y[j] - mu) * is * g2v[j] + b2v[j];
    }

    __shared__ float pp[4][EMB];
#pragma unroll
    for (int j = 0; j < 4; ++j) pp[wave][lane + 64 * j] = pooled[j];
    __syncthreads();
    __shared__ float pool[EMB];
    pool[tid] = (pp[0][tid] + pp[1][tid] + pp[2][tid] + pp[3][tid]) * (1.0f / (float)SEQ);
    __syncthreads();
    if (tid < 10) {
        float o = ob[tid];
        for (int k = 0; k < EMB; ++k) o += pool[k] * ow[tid * EMB + k];
        out[b * 10 + tid] = o;
    }
}

// ---------------------------------------------------------------- launch
extern "C" void kernel_launch(void* const* d_in, const int* in_sizes, int n_in,
                              void* d_out, int out_size, void* d_ws, size_t ws_size,
                              hipStream_t stream)
{
    const float* x      = (const float*)d_in[0];
    const float* conv_w = (const float*)d_in[1];
    const float* conv_b = (const float*)d_in[2];
    const float* bn_g   = (const float*)d_in[3];
    const float* bn_b   = (const float*)d_in[4];
    const float* bn_m   = (const float*)d_in[5];
    const float* bn_v   = (const float*)d_in[6];
    const float* wq1    = (const float*)d_in[7];
    const float* wk1    = (const float*)d_in[8];
    const float* wv1    = (const float*)d_in[9];
    const float* lnA1_g = (const float*)d_in[10];
    const float* lnA1_b = (const float*)d_in[11];
    const float* wq2    = (const float*)d_in[12];
    const float* wk2    = (const float*)d_in[13];
    const float* wv2    = (const float*)d_in[14];
    const float* lnA2_g = (const float*)d_in[15];
    const float* lnA2_b = (const float*)d_in[16];
    const float* ln2_g  = (const float*)d_in[17];
    const float* ln2_b  = (const float*)d_in[18];
    const float* out_w  = (const float*)d_in[19];
    const float* out_b  = (const float*)d_in[20];
    float* out = (float*)d_out;

    const size_t peN = (size_t)SEQ * EMB;
    const size_t wN  = (size_t)EMB * EMB;

    int chunk = B_TOT;
    while (chunk > 1) {
        size_t M    = (size_t)chunk * SEQ;
        size_t Mpad = (M + 127) / 128 * 128;
        size_t need = peN * 4 + 6 * wN * 2 + (Mpad + 4 * M) * EMB * 2;
        if (need <= ws_size) break;
        chunk >>= 1;
    }
    size_t M    = (size_t)chunk * SEQ;
    size_t Mpad = (M + 127) / 128 * 128;

    float*          pe = (float*)d_ws;
    __hip_bfloat16* Wb = (__hip_bfloat16*)(pe + peN);
    __hip_bfloat16* Xb = Wb + 6 * wN;
    __hip_bfloat16* Ob = Xb + Mpad * EMB;
    __hip_bfloat16* Qb = Ob + M * EMB;
    __hip_bfloat16* Kb = Qb + M * EMB;
    __hip_bfloat16* Vb = Kb + M * EMB;

    pe_kernel<<<(SEQ * EMB + 255) / 256, 256, 0, stream>>>(pe);
    {
        dim3 cg((unsigned)(wN / 1024), 6);
        cvt6_kernel<<<cg, 256, 0, stream>>>(wq1, wk1, wv1, wq2, wk2, wv2, Wb, (int)wN);
    }

    for (int b0 = 0; b0 < B_TOT; b0 += chunk) {
        int Bc = chunk;
        int Mi = Bc * SEQ;
        dim3 ggrid((unsigned)(Mpad / 128), 6);

        embed_kernel<<<Bc * SEQ, 256, 0, stream>>>(
            x + (size_t)b0 * LIN, conv_w, conv_b, bn_g, bn_b, bn_m, bn_v, pe, Xb);

        // --- attention block 1 ---
        gemm_qkv_mfma<<<ggrid, 256, 0, stream>>>(Xb, Wb, Qb, Kb, Vb, Mi);
        attn_mfma_kernel<<<Bc * HEADS, 256, 0, stream>>>(Qb, Kb, Vb, Ob);
        ln_pe4_kernel<<<(Mi + 3) / 4, 256, 0, stream>>>(Ob, lnA1_g, lnA1_b, pe, Xb, Mi);

        // --- attention block 2 ---
        gemm_qkv_mfma<<<ggrid, 256, 0, stream>>>(Xb, Wb + 3 * wN, Qb, Kb, Vb, Mi);
        attn_mfma_kernel<<<Bc * HEADS, 256, 0, stream>>>(Qb, Kb, Vb, Ob);
        lnfc_kernel<<<Bc, 256, 0, stream>>>(Ob, lnA2_g, lnA2_b, ln2_g, ln2_b,
                                            out_w, out_b, out + (size_t)b0 * 10);
    }
}

// Round 11
// 433.508 us; speedup vs baseline: 1.0264x; 1.0264x over previous
//
#include <hip/hip_runtime.h>
#include <hip/hip_bf16.h>
#include <math.h>

#define B_TOT 512
#define SEQ   179
#define EMB   256
#define HEADS 8
#define HD    32
#define LIN   720
#define EPSV  1e-5f

typedef __attribute__((ext_vector_type(8))) short bf16x8;
typedef __attribute__((ext_vector_type(4))) float f32x4;

__device__ __forceinline__ short f2bf(float f) {          // RNE f32->bf16 bits
    unsigned u = __float_as_uint(f);
    return (short)((u + 0x7fff + ((u >> 16) & 1)) >> 16);
}
__device__ __forceinline__ unsigned cvt_pk_bf16(float lo, float hi) {
    unsigned r;
    asm("v_cvt_pk_bf16_f32 %0, %1, %2" : "=v"(r) : "v"(lo), "v"(hi));
    return r;
}

// ---------------------------------------------------------------- PE table
__global__ void pe_kernel(float* __restrict__ pe) {
    int idx = blockIdx.x * 256 + threadIdx.x;
    if (idx >= SEQ * EMB) return;
    int s = idx / EMB, e = idx % EMB;
    int i = e >> 1;
    float dv  = expf((float)(2 * i) * (-9.210340371976184f / (float)EMB));
    float ang = (float)s * dv * ((float)EMB / (float)SEQ);
    pe[idx] = (e & 1) ? cosf(ang) : sinf(ang);
}

// ------------------------------------- f32 -> bf16 convert, 6 weights at once
__global__ void cvt6_kernel(const float* __restrict__ s0, const float* __restrict__ s1,
                            const float* __restrict__ s2, const float* __restrict__ s3,
                            const float* __restrict__ s4, const float* __restrict__ s5,
                            __hip_bfloat16* __restrict__ dst, int n) {
    int w = blockIdx.y;
    const float* src = (w == 0) ? s0 : (w == 1) ? s1 : (w == 2) ? s2
                     : (w == 3) ? s3 : (w == 4) ? s4 : s5;
    __hip_bfloat16* d = dst + (size_t)w * n;
    int i = (blockIdx.x * 256 + threadIdx.x) * 4;
    if (i < n) {
        float4 v = *reinterpret_cast<const float4*>(&src[i]);
        d[i + 0] = __float2bfloat16(v.x);
        d[i + 1] = __float2bfloat16(v.y);
        d[i + 2] = __float2bfloat16(v.z);
        d[i + 3] = __float2bfloat16(v.w);
    }
}

// ------------ conv(stride4,K8) + BN + ReLU + PE -> bf16, wave-per-row x4
__global__ __launch_bounds__(256) void embed_kernel(
    const float* __restrict__ x, const float* __restrict__ cw,
    const float* __restrict__ cb, const float* __restrict__ g,
    const float* __restrict__ bb, const float* __restrict__ mean,
    const float* __restrict__ var, const float* __restrict__ pe,
    __hip_bfloat16* __restrict__ Xb, int M)
{
    int r = blockIdx.x * 4 + (threadIdx.x >> 6);
    if (r >= M) return;
    int lane = threadIdx.x & 63;
    int b = r / SEQ, s = r - b * SEQ;
    int e0 = lane * 4;

    const float* xr = &x[(size_t)b * LIN + s * 4];
    float4 xa = *reinterpret_cast<const float4*>(xr);
    float4 xc = *reinterpret_cast<const float4*>(xr + 4);
    float xin[8] = {xa.x, xa.y, xa.z, xa.w, xc.x, xc.y, xc.z, xc.w};

    float gv[4], bv[4], mv[4], vv[4], cbv[4], pv[4];
    *reinterpret_cast<float4*>(gv)  = *reinterpret_cast<const float4*>(&g[e0]);
    *reinterpret_cast<float4*>(bv)  = *reinterpret_cast<const float4*>(&bb[e0]);
    *reinterpret_cast<float4*>(mv)  = *reinterpret_cast<const float4*>(&mean[e0]);
    *reinterpret_cast<float4*>(vv)  = *reinterpret_cast<const float4*>(&var[e0]);
    *reinterpret_cast<float4*>(cbv) = *reinterpret_cast<const float4*>(&cb[e0]);
    *reinterpret_cast<float4*>(pv)  = *reinterpret_cast<const float4*>(&pe[s * EMB + e0]);

    float y[4];
#pragma unroll
    for (int c = 0; c < 4; ++c) {
        int e = e0 + c;
        float4 w0 = *reinterpret_cast<const float4*>(&cw[e * 8]);
        float4 w1 = *reinterpret_cast<const float4*>(&cw[e * 8 + 4]);
        float acc = cbv[c]
            + xin[0]*w0.x + xin[1]*w0.y + xin[2]*w0.z + xin[3]*w0.w
            + xin[4]*w1.x + xin[5]*w1.y + xin[6]*w1.z + xin[7]*w1.w;
        acc = (acc - mv[c]) * (gv[c] * rsqrtf(vv[c] + EPSV)) + bv[c];
        acc = fmaxf(acc, 0.f);
        y[c] = acc + pv[c];
    }
    uint2 o;
    o.x = cvt_pk_bf16(y[0], y[1]);
    o.y = cvt_pk_bf16(y[2], y[3]);
    *reinterpret_cast<uint2*>(&Xb[(size_t)r * EMB + e0]) = o;
}

// ---------------- MFMA bf16 GEMM: C[m,n] = sum_k A[m,k] * W[n,k], C in bf16
__global__ __launch_bounds__(256) void gemm_qkv_mfma(
    const __hip_bfloat16* __restrict__ A,    // [Mpad][256]
    const __hip_bfloat16* __restrict__ Wset, // [3][256][256]
    __hip_bfloat16* __restrict__ Q, __hip_bfloat16* __restrict__ K,
    __hip_bfloat16* __restrict__ V, int M)
{
    int by = blockIdx.y;                       // 0..5
    int wsel = by >> 1;
    const __hip_bfloat16* W = Wset + (size_t)wsel * EMB * EMB;
    __hip_bfloat16* C = (wsel == 0) ? Q : (wsel == 1 ? K : V);
    int nbase = (by & 1) * 128;
    int mbase = blockIdx.x * 128;

    __shared__ __hip_bfloat16 As[128][64];
    __shared__ __hip_bfloat16 Bs[128][64];

    int tid  = threadIdx.x;
    int wave = tid >> 6, lane = tid & 63;
    int wr = wave >> 1, wc = wave & 1;

    int r0   = tid >> 3;
    int srcs = (tid & 7) ^ (r0 & 7);
    const __hip_bfloat16* gA = A + (size_t)(mbase + r0) * EMB + srcs * 8;
    const __hip_bfloat16* gB = W + (size_t)(nbase + r0) * EMB + srcs * 8;

    f32x4 acc[4][4];
#pragma unroll
    for (int i = 0; i < 4; ++i)
#pragma unroll
        for (int j = 0; j < 4; ++j) acc[i][j] = (f32x4){0.f, 0.f, 0.f, 0.f};

    for (int kt = 0; kt < EMB; kt += 64) {
        if (kt) __syncthreads();
#pragma unroll
        for (int i = 0; i < 4; ++i) {
            __hip_bfloat16* l = &As[0][0] + i * 2048 + tid * 8;
            __builtin_amdgcn_global_load_lds(
                (const __attribute__((address_space(1))) void*)(gA + (size_t)i * 32 * EMB + kt),
                (__attribute__((address_space(3))) void*)l, 16, 0, 0);
        }
#pragma unroll
        for (int i = 0; i < 4; ++i) {
            __hip_bfloat16* l = &Bs[0][0] + i * 2048 + tid * 8;
            __builtin_amdgcn_global_load_lds(
                (const __attribute__((address_space(1))) void*)(gB + (size_t)i * 32 * EMB + kt),
                (__attribute__((address_space(3))) void*)l, 16, 0, 0);
        }
        asm volatile("s_waitcnt vmcnt(0)" ::: "memory");
        __syncthreads();

#pragma unroll
        for (int kk = 0; kk < 2; ++kk) {
            bf16x8 af[4], bfr[4];
            int sg = kk * 4 + (lane >> 4);
#pragma unroll
            for (int mi = 0; mi < 4; ++mi) {
                int row = wr * 64 + mi * 16 + (lane & 15);
                int sl  = sg ^ (row & 7);
                af[mi] = *reinterpret_cast<const bf16x8*>(&As[row][sl * 8]);
            }
#pragma unroll
            for (int ni = 0; ni < 4; ++ni) {
                int row = wc * 64 + ni * 16 + (lane & 15);
                int sl  = sg ^ (row & 7);
                bfr[ni] = *reinterpret_cast<const bf16x8*>(&Bs[row][sl * 8]);
            }
#pragma unroll
            for (int mi = 0; mi < 4; ++mi)
#pragma unroll
                for (int ni = 0; ni < 4; ++ni)
                    acc[mi][ni] = __builtin_amdgcn_mfma_f32_16x16x32_bf16(
                        af[mi], bfr[ni], acc[mi][ni], 0, 0, 0);
        }
    }

    int rg = lane >> 4, cli = lane & 15;
#pragma unroll
    for (int mi = 0; mi < 4; ++mi)
#pragma unroll
        for (int j = 0; j < 4; ++j) {
            int m = mbase + wr * 64 + mi * 16 + rg * 4 + j;
            if (m < M) {
#pragma unroll
                for (int ni = 0; ni < 4; ++ni)
                    C[(size_t)m * EMB + nbase + wc * 64 + ni * 16 + cli] =
                        __float2bfloat16(acc[mi][ni][j]);
            }
        }
}

// ---------------- MFMA flash attention v4: register-P via ds_bpermute,
// O^T-form PV (q lane-local end to end), no P-LDS, no lgkm stalls.
// Block per (b,h), 4 waves x 48 q-rows. LDS 25.6KB.
__global__ __launch_bounds__(256) void attn_mfma_kernel(
    const __hip_bfloat16* __restrict__ Qb, const __hip_bfloat16* __restrict__ Kb,
    const __hip_bfloat16* __restrict__ Vb, __hip_bfloat16* __restrict__ O)
{
    int bh = blockIdx.x;
    int b = bh >> 3, h = bh & 7;
    const size_t base = (size_t)b * SEQ * EMB + (size_t)h * HD;

    // K2: row = t>>1, slot = (t&1)*4 + d/8, phys = slot^(row&7)   (12288 B)
    __shared__ short K2[96][64];
    // Vt: V^T row-major [d][t], stride 208 shorts (13312 B); b128 reads at floor
    __shared__ short Vt[32][208];

    int tid  = threadIdx.x;
    int wave = tid >> 6, lane = tid & 63;
    int cl = lane & 15, rg = lane >> 4;

    // ---- stage K (swizzled b128 writes), all threads
    for (int u = tid; u < 192 * 4; u += 256) {
        int t = u >> 2, d0 = (u & 3) << 3;
        uint4 kv = make_uint4(0, 0, 0, 0);
        if (t < SEQ) kv = *reinterpret_cast<const uint4*>(&Kb[base + (size_t)t * EMB + d0]);
        int krow = t >> 1;
        int kphy = (((t & 1) * 4 + (d0 >> 3)) ^ (krow & 7));
        *reinterpret_cast<uint4*>(&K2[krow][kphy * 8]) = kv;
    }
    // ---- stage V^T: register quad-transpose, conflict-free b64 writes
    if (tid < 192) {                       // waves 0..2 (wave-uniform branch)
        int tq = tid >> 2, d0 = (tid & 3) << 3;
        int t0 = tq * 4;
        uint4 r0 = make_uint4(0,0,0,0), r1 = r0, r2 = r0, r3 = r0;
        if (t0 + 0 < SEQ) r0 = *reinterpret_cast<const uint4*>(&Vb[base + (size_t)(t0+0)*EMB + d0]);
        if (t0 + 1 < SEQ) r1 = *reinterpret_cast<const uint4*>(&Vb[base + (size_t)(t0+1)*EMB + d0]);
        if (t0 + 2 < SEQ) r2 = *reinterpret_cast<const uint4*>(&Vb[base + (size_t)(t0+2)*EMB + d0]);
        if (t0 + 3 < SEQ) r3 = *reinterpret_cast<const uint4*>(&Vb[base + (size_t)(t0+3)*EMB + d0]);
        const unsigned* q0 = reinterpret_cast<const unsigned*>(&r0);
        const unsigned* q1 = reinterpret_cast<const unsigned*>(&r1);
        const unsigned* q2 = reinterpret_cast<const unsigned*>(&r2);
        const unsigned* q3 = reinterpret_cast<const unsigned*>(&r3);
#pragma unroll
        for (int k = 0; k < 8; ++k) {
            int dw = k >> 1, sh = (k & 1) * 16;
            unsigned a0 = (q0[dw] >> sh) & 0xffffu;
            unsigned a1 = (q1[dw] >> sh) & 0xffffu;
            unsigned a2 = (q2[dw] >> sh) & 0xffffu;
            unsigned a3 = (q3[dw] >> sh) & 0xffffu;
            uint2 w;
            w.x = a0 | (a1 << 16);
            w.y = a2 | (a3 << 16);
            *reinterpret_cast<uint2*>(&Vt[d0 + k][t0]) = w;
        }
    }
    __syncthreads();

    const float csw2 = (0.0625f / (float)SEQ) * 1.4426950408889634f;
    // bpermute lane maps (byte addrs), hoisted per-lane constants
    int srcA4 = ((((rg & 1) << 5) + cl) << 2);   // d0,d1 sources
    int srcB4 = srcA4 + 64;                      // d2,d3 sources (+16 lanes)
    bool hi2  = (rg >= 2);

    for (int qt = 0; qt < 3; ++qt) {
        int qbase = wave * 48 + qt * 16;
        int sq = qbase + cl;
        bf16x8 aq = {};
        if (sq < SEQ)
            aq = *reinterpret_cast<const bf16x8*>(&Qb[base + (size_t)sq * EMB + rg * 8]);
        float sf = (float)sq;

        f32x4 olo = {0.f, 0.f, 0.f, 0.f}, ohi = {0.f, 0.f, 0.f, 0.f};
        float lrow = 0.f;

#pragma unroll
        for (int blk = 0; blk < 6; ++blk) {
            // ---- K^T Q for two 16-t tiles (C: lane q=cl, t=rg*4+j)
            f32x4 s1, s2;
            {
                int t = blk * 32 + cl;
                int kr = t >> 1;
                int kph = (((t & 1) * 4 + rg) ^ (kr & 7));
                bf16x8 kf = *reinterpret_cast<const bf16x8*>(&K2[kr][kph * 8]);
                s1 = __builtin_amdgcn_mfma_f32_16x16x32_bf16(
                    kf, aq, (f32x4){0.f, 0.f, 0.f, 0.f}, 0, 0, 0);
            }
            {
                int t = blk * 32 + 16 + cl;
                int kr = t >> 1;
                int kph = (((t & 1) * 4 + rg) ^ (kr & 7));
                bf16x8 kf = *reinterpret_cast<const bf16x8*>(&K2[kr][kph * 8]);
                s2 = __builtin_amdgcn_mfma_f32_16x16x32_bf16(
                    kf, aq, (f32x4){0.f, 0.f, 0.f, 0.f}, 0, 0, 0);
            }

            // ---- weight + exp (no-max softmax: |logit| <= ~0.2)
            int tb1 = blk * 32 + rg * 4;
            int tb2 = tb1 + 16;
            float p1[4], p2[4];
#pragma unroll
            for (int j = 0; j < 4; ++j) {
                p1[j] = exp2f(s1[j] * (fabsf(sf - (float)(tb1 + j)) * csw2));
                p2[j] = exp2f(s2[j] * (fabsf(sf - (float)(tb2 + j)) * csw2));
            }
            if (blk == 5) {                       // only tile2 holds t >= SEQ
#pragma unroll
                for (int j = 0; j < 4; ++j)
                    if (tb2 + j >= SEQ) p2[j] = 0.f;
            }
            lrow += (p1[0] + p1[1]) + (p1[2] + p1[3])
                  + (p2[0] + p2[1]) + (p2[2] + p2[3]);

            // ---- pack + in-register P-frag regroup (t: rg*4 -> rg*8 order)
            int w10 = (int)cvt_pk_bf16(p1[0], p1[1]);
            int w11 = (int)cvt_pk_bf16(p1[2], p1[3]);
            int w20 = (int)cvt_pk_bf16(p2[0], p2[1]);
            int w21 = (int)cvt_pk_bf16(p2[2], p2[3]);
            int d0a = __builtin_amdgcn_ds_bpermute(srcA4, w10);
            int d0b = __builtin_amdgcn_ds_bpermute(srcA4, w20);
            int d1a = __builtin_amdgcn_ds_bpermute(srcA4, w11);
            int d1b = __builtin_amdgcn_ds_bpermute(srcA4, w21);
            int d2a = __builtin_amdgcn_ds_bpermute(srcB4, w10);
            int d2b = __builtin_amdgcn_ds_bpermute(srcB4, w20);
            int d3a = __builtin_amdgcn_ds_bpermute(srcB4, w11);
            int d3b = __builtin_amdgcn_ds_bpermute(srcB4, w21);
            uint4 pw;
            pw.x = (unsigned)(hi2 ? d0b : d0a);
            pw.y = (unsigned)(hi2 ? d1b : d1a);
            pw.z = (unsigned)(hi2 ? d2b : d2a);
            pw.w = (unsigned)(hi2 ? d3b : d3a);
            bf16x8 pfrag = *reinterpret_cast<bf16x8*>(&pw);

            // ---- PV: O^T[d][q] += V^T[d][t] * P^T[t][q]
            bf16x8 vlo = *reinterpret_cast<const bf16x8*>(&Vt[cl][blk * 32 + rg * 8]);
            bf16x8 vhi = *reinterpret_cast<const bf16x8*>(&Vt[cl + 16][blk * 32 + rg * 8]);
            olo = __builtin_amdgcn_mfma_f32_16x16x32_bf16(vlo, pfrag, olo, 0, 0, 0);
            ohi = __builtin_amdgcn_mfma_f32_16x16x32_bf16(vhi, pfrag, ohi, 0, 0, 0);
        }

        // ---- row sum: q=cl is lane-local; reduce over the 4 rg groups
        lrow += __shfl_xor(lrow, 16);
        lrow += __shfl_xor(lrow, 32);

        // ---- store: lane owns O[q=sq][d = rg*4..+3 and +16], b64 each
        if (sq < SEQ) {
            float rl = 1.0f / lrow;
            __hip_bfloat16* op = &O[base + (size_t)sq * EMB];
            uint2 wlo, whi;
            wlo.x = cvt_pk_bf16(olo[0] * rl, olo[1] * rl);
            wlo.y = cvt_pk_bf16(olo[2] * rl, olo[3] * rl);
            whi.x = cvt_pk_bf16(ohi[0] * rl, ohi[1] * rl);
            whi.y = cvt_pk_bf16(ohi[2] * rl, ohi[3] * rl);
            *reinterpret_cast<uint2*>(&op[rg * 4])      = wlo;
            *reinterpret_cast<uint2*>(&op[16 + rg * 4]) = whi;
        }
    }
}

// ---------------- row LayerNorm + PE: wave-per-row, 4 rows/block, bf16 io
__global__ __launch_bounds__(256) void ln_pe4_kernel(
    const __hip_bfloat16* __restrict__ X, const float* __restrict__ g,
    const float* __restrict__ bb, const float* __restrict__ pe,
    __hip_bfloat16* __restrict__ Xb, int M)
{
    int r = blockIdx.x * 4 + (threadIdx.x >> 6);
    if (r >= M) return;
    int lane = threadIdx.x & 63;
    int s = r % SEQ;
    int c0 = lane * 4;

    uint2 raw = *reinterpret_cast<const uint2*>(&X[(size_t)r * EMB + c0]);
    float v[4];
    v[0] = __uint_as_float((raw.x & 0xffffu) << 16);
    v[1] = __uint_as_float(raw.x & 0xffff0000u);
    v[2] = __uint_as_float((raw.y & 0xffffu) << 16);
    v[3] = __uint_as_float(raw.y & 0xffff0000u);

    float sum = v[0] + v[1] + v[2] + v[3];
    float sq  = v[0]*v[0] + v[1]*v[1] + v[2]*v[2] + v[3]*v[3];
#pragma unroll
    for (int off = 32; off > 0; off >>= 1) {
        sum += __shfl_xor(sum, off);
        sq  += __shfl_xor(sq,  off);
    }
    float mu  = sum * (1.0f / EMB);
    float var = sq * (1.0f / EMB) - mu * mu;
    float is  = rsqrtf(var + EPSV);

    float4 gv = *reinterpret_cast<const float4*>(&g[c0]);
    float4 bv = *reinterpret_cast<const float4*>(&bb[c0]);
    float4 pv = *reinterpret_cast<const float4*>(&pe[s * EMB + c0]);
    float y0 = (v[0] - mu) * is * gv.x + bv.x + pv.x;
    float y1 = (v[1] - mu) * is * gv.y + bv.y + pv.y;
    float y2 = (v[2] - mu) * is * gv.z + bv.z + pv.z;
    float y3 = (v[3] - mu) * is * gv.w + bv.w + pv.w;

    uint2 o;
    o.x = cvt_pk_bf16(y0, y1);
    o.y = cvt_pk_bf16(y2, y3);
    *reinterpret_cast<uint2*>(&Xb[(size_t)r * EMB + c0]) = o;
}

// ------- fused: LN(lnA2) -> LN(ln2) -> mean-pool over SEQ -> FC[10], 8 waves
__global__ __launch_bounds__(512) void lnfc_kernel(
    const __hip_bfloat16* __restrict__ X,
    const float* __restrict__ g1, const float* __restrict__ b1,
    const float* __restrict__ g2, const float* __restrict__ b2,
    const float* __restrict__ ow, const float* __restrict__ ob,
    float* __restrict__ out)
{
    int b    = blockIdx.x;
    int tid  = threadIdx.x;
    int wave = tid >> 6, lane = tid & 63;

    float g1v[4], b1v[4], g2v[4], b2v[4], pooled[4];
#pragma unroll
    for (int j = 0; j < 4; ++j) {
        int c = lane + 64 * j;
        g1v[j] = g1[c]; b1v[j] = b1[c];
        g2v[j] = g2[c]; b2v[j] = b2[c];
        pooled[j] = 0.f;
    }

    for (int s = wave; s < SEQ; s += 8) {
        const __hip_bfloat16* row = &X[((size_t)b * SEQ + s) * EMB];
        float v[4];
#pragma unroll
        for (int j = 0; j < 4; ++j) v[j] = __bfloat162float(row[lane + 64 * j]);

        float sum = v[0] + v[1] + v[2] + v[3];
        float sq  = v[0]*v[0] + v[1]*v[1] + v[2]*v[2] + v[3]*v[3];
#pragma unroll
        for (int off = 32; off > 0; off >>= 1) {
            sum += __shfl_xor(sum, off);
            sq  += __shfl_xor(sq,  off);
        }
        float mu  = sum * (1.0f / EMB);
        float var = sq * (1.0f / EMB) - mu * mu;
        float is  = rsqrtf(var + EPSV);
        float y[4];
#pragma unroll
        for (int j = 0; j < 4; ++j) y[j] = (v[j] - mu) * is * g1v[j] + b1v[j];

        sum = y[0] + y[1] + y[2] + y[3];
        sq  = y[0]*y[0] + y[1]*y[1] + y[2]*y[2] + y[3]*y[3];
#pragma unroll
        for (int off = 32; off > 0; off >>= 1) {
            sum += __shfl_xor(sum, off);
            sq  += __shfl_xor(sq,  off);
        }
        mu  = sum * (1.0f / EMB);
        var = sq * (1.0f / EMB) - mu * mu;
        is  = rsqrtf(var + EPSV);
#pragma unroll
        for (int j = 0; j < 4; ++j) pooled[j] += (y[j] - mu) * is * g2v[j] + b2v[j];
    }

    __shared__ float pp[8][EMB];
#pragma unroll
    for (int j = 0; j < 4; ++j) pp[wave][lane + 64 * j] = pooled[j];
    __syncthreads();
    __shared__ float pool[EMB];
    if (tid < EMB) {
        float pl = 0.f;
#pragma unroll
        for (int w = 0; w < 8; ++w) pl += pp[w][tid];
        pool[tid] = pl * (1.0f / (float)SEQ);
    }
    __syncthreads();
    if (tid < 10) {
        float o = ob[tid];
        for (int k = 0; k < EMB; ++k) o += pool[k] * ow[tid * EMB + k];
        out[b * 10 + tid] = o;
    }
}

// ---------------------------------------------------------------- launch
extern "C" void kernel_launch(void* const* d_in, const int* in_sizes, int n_in,
                              void* d_out, int out_size, void* d_ws, size_t ws_size,
                              hipStream_t stream)
{
    const float* x      = (const float*)d_in[0];
    const float* conv_w = (const float*)d_in[1];
    const float* conv_b = (const float*)d_in[2];
    const float* bn_g   = (const float*)d_in[3];
    const float* bn_b   = (const float*)d_in[4];
    const float* bn_m   = (const float*)d_in[5];
    const float* bn_v   = (const float*)d_in[6];
    const float* wq1    = (const float*)d_in[7];
    const float* wk1    = (const float*)d_in[8];
    const float* wv1    = (const float*)d_in[9];
    const float* lnA1_g = (const float*)d_in[10];
    const float* lnA1_b = (const float*)d_in[11];
    const float* wq2    = (const float*)d_in[12];
    const float* wk2    = (const float*)d_in[13];
    const float* wv2    = (const float*)d_in[14];
    const float* lnA2_g = (const float*)d_in[15];
    const float* lnA2_b = (const float*)d_in[16];
    const float* ln2_g  = (const float*)d_in[17];
    const float* ln2_b  = (const float*)d_in[18];
    const float* out_w  = (const float*)d_in[19];
    const float* out_b  = (const float*)d_in[20];
    float* out = (float*)d_out;

    const size_t peN = (size_t)SEQ * EMB;
    const size_t wN  = (size_t)EMB * EMB;

    int chunk = B_TOT;
    while (chunk > 1) {
        size_t M    = (size_t)chunk * SEQ;
        size_t Mpad = (M + 127) / 128 * 128;
        size_t need = peN * 4 + 6 * wN * 2 + (Mpad + 4 * M) * EMB * 2;
        if (need <= ws_size) break;
        chunk >>= 1;
    }
    size_t M    = (size_t)chunk * SEQ;
    size_t Mpad = (M + 127) / 128 * 128;

    float*          pe = (float*)d_ws;
    __hip_bfloat16* Wb = (__hip_bfloat16*)(pe + peN);
    __hip_bfloat16* Xb = Wb + 6 * wN;
    __hip_bfloat16* Ob = Xb + Mpad * EMB;
    __hip_bfloat16* Qb = Ob + M * EMB;
    __hip_bfloat16* Kb = Qb + M * EMB;
    __hip_bfloat16* Vb = Kb + M * EMB;

    pe_kernel<<<(SEQ * EMB + 255) / 256, 256, 0, stream>>>(pe);
    {
        dim3 cg((unsigned)(wN / 1024), 6);
        cvt6_kernel<<<cg, 256, 0, stream>>>(wq1, wk1, wv1, wq2, wk2, wv2, Wb, (int)wN);
    }

    for (int b0 = 0; b0 < B_TOT; b0 += chunk) {
        int Bc = chunk;
        int Mi = Bc * SEQ;
        dim3 ggrid((unsigned)(Mpad / 128), 6);

        embed_kernel<<<(Mi + 3) / 4, 256, 0, stream>>>(
            x + (size_t)b0 * LIN, conv_w, conv_b, bn_g, bn_b, bn_m, bn_v, pe, Xb, Mi);

        // --- attention block 1 ---
        gemm_qkv_mfma<<<ggrid, 256, 0, stream>>>(Xb, Wb, Qb, Kb, Vb, Mi);
        attn_mfma_kernel<<<Bc * HEADS, 256, 0, stream>>>(Qb, Kb, Vb, Ob);
        ln_pe4_kernel<<<(Mi + 3) / 4, 256, 0, stream>>>(Ob, lnA1_g, lnA1_b, pe, Xb, Mi);

        // --- attention block 2 ---
        gemm_qkv_mfma<<<ggrid, 256, 0, stream>>>(Xb, Wb + 3 * wN, Qb, Kb, Vb, Mi);
        attn_mfma_kernel<<<Bc * HEADS, 256, 0, stream>>>(Qb, Kb, Vb, Ob);
        lnfc_kernel<<<Bc, 512, 0, stream>>>(Ob, lnA2_g, lnA2_b, ln2_g, ln2_b,
                                            out_w, out_b, out + (size_t)b0 * 10);
    }
}

// Round 12
// 360.717 us; speedup vs baseline: 1.2335x; 1.2018x over previous
//
#include <hip/hip_runtime.h>
#include <hip/hip_bf16.h>
#include <math.h>

#define B_TOT 512
#define SEQ   179
#define EMB   256
#define HEADS 8
#define HD    32
#define LIN   720
#define EPSV  1e-5f

typedef __attribute__((ext_vector_type(8))) short bf16x8;
typedef __attribute__((ext_vector_type(4))) float f32x4;

__device__ __forceinline__ short f2bf(float f) {          // RNE f32->bf16 bits
    unsigned u = __float_as_uint(f);
    return (short)((u + 0x7fff + ((u >> 16) & 1)) >> 16);
}
__device__ __forceinline__ unsigned cvt_pk_bf16(float lo, float hi) {
    unsigned r;
    asm("v_cvt_pk_bf16_f32 %0, %1, %2" : "=v"(r) : "v"(lo), "v"(hi));
    return r;
}

// ---------------------------------------------------------------- PE table
__global__ void pe_kernel(float* __restrict__ pe) {
    int idx = blockIdx.x * 256 + threadIdx.x;
    if (idx >= SEQ * EMB) return;
    int s = idx / EMB, e = idx % EMB;
    int i = e >> 1;
    float dv  = expf((float)(2 * i) * (-9.210340371976184f / (float)EMB));
    float ang = (float)s * dv * ((float)EMB / (float)SEQ);
    pe[idx] = (e & 1) ? cosf(ang) : sinf(ang);
}

// --------------- one-time: fold BN into conv weights; wt transposed [8][256]
__global__ void fold_conv_kernel(const float* __restrict__ cw, const float* __restrict__ cb,
                                 const float* __restrict__ g, const float* __restrict__ bb,
                                 const float* __restrict__ mean, const float* __restrict__ var,
                                 float* __restrict__ wt, float* __restrict__ bp) {
    int e = threadIdx.x;                  // 256 threads, 1 block
    float is = g[e] * rsqrtf(var[e] + EPSV);
#pragma unroll
    for (int j = 0; j < 8; ++j) wt[j * EMB + e] = cw[e * 8 + j] * is;
    bp[e] = (cb[e] - mean[e]) * is + bb[e];
}

// ------------------------------------- f32 -> bf16 convert, 6 weights at once
__global__ void cvt6_kernel(const float* __restrict__ s0, const float* __restrict__ s1,
                            const float* __restrict__ s2, const float* __restrict__ s3,
                            const float* __restrict__ s4, const float* __restrict__ s5,
                            __hip_bfloat16* __restrict__ dst, int n) {
    int w = blockIdx.y;
    const float* src = (w == 0) ? s0 : (w == 1) ? s1 : (w == 2) ? s2
                     : (w == 3) ? s3 : (w == 4) ? s4 : s5;
    __hip_bfloat16* d = dst + (size_t)w * n;
    int i = (blockIdx.x * 256 + threadIdx.x) * 4;
    if (i < n) {
        float4 v = *reinterpret_cast<const float4*>(&src[i]);
        d[i + 0] = __float2bfloat16(v.x);
        d[i + 1] = __float2bfloat16(v.y);
        d[i + 2] = __float2bfloat16(v.z);
        d[i + 3] = __float2bfloat16(v.w);
    }
}

// ------------ embed v3: conv(stride4,K8,BN-folded) + ReLU + PE -> bf16
// block = 16 rows (4/wave); lane owns 4 cols; weights hoisted to registers.
__global__ __launch_bounds__(256) void embed_kernel(
    const float* __restrict__ x, const float* __restrict__ wt,
    const float* __restrict__ bp, const float* __restrict__ pe,
    __hip_bfloat16* __restrict__ Xb, int M)
{
    int lane = threadIdx.x & 63;
    int wv   = threadIdx.x >> 6;
    int e0   = lane * 4;

    float wreg[8][4];
#pragma unroll
    for (int j = 0; j < 8; ++j)
        *reinterpret_cast<float4*>(wreg[j]) = *reinterpret_cast<const float4*>(&wt[j * EMB + e0]);
    float4 bpv = *reinterpret_cast<const float4*>(&bp[e0]);

    int r0 = blockIdx.x * 16 + wv * 4;
#pragma unroll
    for (int rr = 0; rr < 4; ++rr) {
        int r = r0 + rr;
        if (r >= M) return;               // rows ascend; safe early-out
        int b = r / SEQ, s = r - b * SEQ;
        const float* xr = &x[(size_t)b * LIN + s * 4];
        float4 xa = *reinterpret_cast<const float4*>(xr);
        float4 xc = *reinterpret_cast<const float4*>(xr + 4);
        float xi[8] = {xa.x, xa.y, xa.z, xa.w, xc.x, xc.y, xc.z, xc.w};
        float4 pv = *reinterpret_cast<const float4*>(&pe[s * EMB + e0]);
        const float* bpa = reinterpret_cast<const float*>(&bpv);
        const float* pva = reinterpret_cast<const float*>(&pv);
        float y[4];
#pragma unroll
        for (int c = 0; c < 4; ++c) {
            float acc = bpa[c];
#pragma unroll
            for (int j = 0; j < 8; ++j) acc += xi[j] * wreg[j][c];
            y[c] = fmaxf(acc, 0.f) + pva[c];
        }
        uint2 o;
        o.x = cvt_pk_bf16(y[0], y[1]);
        o.y = cvt_pk_bf16(y[2], y[3]);
        *reinterpret_cast<uint2*>(&Xb[(size_t)r * EMB + e0]) = o;
    }
}

// ---------------- MFMA bf16 GEMM: C[m,n] = sum_k A[m,k] * W[n,k], C in bf16
__global__ __launch_bounds__(256) void gemm_qkv_mfma(
    const __hip_bfloat16* __restrict__ A,    // [Mpad][256]
    const __hip_bfloat16* __restrict__ Wset, // [3][256][256]
    __hip_bfloat16* __restrict__ Q, __hip_bfloat16* __restrict__ K,
    __hip_bfloat16* __restrict__ V, int M)
{
    int by = blockIdx.y;                       // 0..5
    int wsel = by >> 1;
    const __hip_bfloat16* W = Wset + (size_t)wsel * EMB * EMB;
    __hip_bfloat16* C = (wsel == 0) ? Q : (wsel == 1 ? K : V);
    int nbase = (by & 1) * 128;
    int mbase = blockIdx.x * 128;

    __shared__ __hip_bfloat16 As[128][64];
    __shared__ __hip_bfloat16 Bs[128][64];

    int tid  = threadIdx.x;
    int wave = tid >> 6, lane = tid & 63;
    int wr = wave >> 1, wc = wave & 1;

    int r0   = tid >> 3;
    int srcs = (tid & 7) ^ (r0 & 7);
    const __hip_bfloat16* gA = A + (size_t)(mbase + r0) * EMB + srcs * 8;
    const __hip_bfloat16* gB = W + (size_t)(nbase + r0) * EMB + srcs * 8;

    f32x4 acc[4][4];
#pragma unroll
    for (int i = 0; i < 4; ++i)
#pragma unroll
        for (int j = 0; j < 4; ++j) acc[i][j] = (f32x4){0.f, 0.f, 0.f, 0.f};

    for (int kt = 0; kt < EMB; kt += 64) {
        if (kt) __syncthreads();
#pragma unroll
        for (int i = 0; i < 4; ++i) {
            __hip_bfloat16* l = &As[0][0] + i * 2048 + tid * 8;
            __builtin_amdgcn_global_load_lds(
                (const __attribute__((address_space(1))) void*)(gA + (size_t)i * 32 * EMB + kt),
                (__attribute__((address_space(3))) void*)l, 16, 0, 0);
        }
#pragma unroll
        for (int i = 0; i < 4; ++i) {
            __hip_bfloat16* l = &Bs[0][0] + i * 2048 + tid * 8;
            __builtin_amdgcn_global_load_lds(
                (const __attribute__((address_space(1))) void*)(gB + (size_t)i * 32 * EMB + kt),
                (__attribute__((address_space(3))) void*)l, 16, 0, 0);
        }
        asm volatile("s_waitcnt vmcnt(0)" ::: "memory");
        __syncthreads();

#pragma unroll
        for (int kk = 0; kk < 2; ++kk) {
            bf16x8 af[4], bfr[4];
            int sg = kk * 4 + (lane >> 4);
#pragma unroll
            for (int mi = 0; mi < 4; ++mi) {
                int row = wr * 64 + mi * 16 + (lane & 15);
                int sl  = sg ^ (row & 7);
                af[mi] = *reinterpret_cast<const bf16x8*>(&As[row][sl * 8]);
            }
#pragma unroll
            for (int ni = 0; ni < 4; ++ni) {
                int row = wc * 64 + ni * 16 + (lane & 15);
                int sl  = sg ^ (row & 7);
                bfr[ni] = *reinterpret_cast<const bf16x8*>(&Bs[row][sl * 8]);
            }
#pragma unroll
            for (int mi = 0; mi < 4; ++mi)
#pragma unroll
                for (int ni = 0; ni < 4; ++ni)
                    acc[mi][ni] = __builtin_amdgcn_mfma_f32_16x16x32_bf16(
                        af[mi], bfr[ni], acc[mi][ni], 0, 0, 0);
        }
    }

    int rg = lane >> 4, cli = lane & 15;
#pragma unroll
    for (int mi = 0; mi < 4; ++mi)
#pragma unroll
        for (int j = 0; j < 4; ++j) {
            int m = mbase + wr * 64 + mi * 16 + rg * 4 + j;
            if (m < M) {
#pragma unroll
                for (int ni = 0; ni < 4; ++ni)
                    C[(size_t)m * EMB + nbase + wc * 64 + ni * 16 + cli] =
                        __float2bfloat16(acc[mi][ni][j]);
            }
        }
}

// ---------------- MFMA flash attention v4: register-P via ds_bpermute,
// O^T-form PV (q lane-local end to end), no P-LDS, no lgkm stalls.
__global__ __launch_bounds__(256) void attn_mfma_kernel(
    const __hip_bfloat16* __restrict__ Qb, const __hip_bfloat16* __restrict__ Kb,
    const __hip_bfloat16* __restrict__ Vb, __hip_bfloat16* __restrict__ O)
{
    int bh = blockIdx.x;
    int b = bh >> 3, h = bh & 7;
    const size_t base = (size_t)b * SEQ * EMB + (size_t)h * HD;

    __shared__ short K2[96][64];
    __shared__ short Vt[32][208];

    int tid  = threadIdx.x;
    int wave = tid >> 6, lane = tid & 63;
    int cl = lane & 15, rg = lane >> 4;

    for (int u = tid; u < 192 * 4; u += 256) {
        int t = u >> 2, d0 = (u & 3) << 3;
        uint4 kv = make_uint4(0, 0, 0, 0);
        if (t < SEQ) kv = *reinterpret_cast<const uint4*>(&Kb[base + (size_t)t * EMB + d0]);
        int krow = t >> 1;
        int kphy = (((t & 1) * 4 + (d0 >> 3)) ^ (krow & 7));
        *reinterpret_cast<uint4*>(&K2[krow][kphy * 8]) = kv;
    }
    if (tid < 192) {
        int tq = tid >> 2, d0 = (tid & 3) << 3;
        int t0 = tq * 4;
        uint4 r0 = make_uint4(0,0,0,0), r1 = r0, r2 = r0, r3 = r0;
        if (t0 + 0 < SEQ) r0 = *reinterpret_cast<const uint4*>(&Vb[base + (size_t)(t0+0)*EMB + d0]);
        if (t0 + 1 < SEQ) r1 = *reinterpret_cast<const uint4*>(&Vb[base + (size_t)(t0+1)*EMB + d0]);
        if (t0 + 2 < SEQ) r2 = *reinterpret_cast<const uint4*>(&Vb[base + (size_t)(t0+2)*EMB + d0]);
        if (t0 + 3 < SEQ) r3 = *reinterpret_cast<const uint4*>(&Vb[base + (size_t)(t0+3)*EMB + d0]);
        const unsigned* q0 = reinterpret_cast<const unsigned*>(&r0);
        const unsigned* q1 = reinterpret_cast<const unsigned*>(&r1);
        const unsigned* q2 = reinterpret_cast<const unsigned*>(&r2);
        const unsigned* q3 = reinterpret_cast<const unsigned*>(&r3);
#pragma unroll
        for (int k = 0; k < 8; ++k) {
            int dw = k >> 1, sh = (k & 1) * 16;
            unsigned a0 = (q0[dw] >> sh) & 0xffffu;
            unsigned a1 = (q1[dw] >> sh) & 0xffffu;
            unsigned a2 = (q2[dw] >> sh) & 0xffffu;
            unsigned a3 = (q3[dw] >> sh) & 0xffffu;
            uint2 w;
            w.x = a0 | (a1 << 16);
            w.y = a2 | (a3 << 16);
            *reinterpret_cast<uint2*>(&Vt[d0 + k][t0]) = w;
        }
    }
    __syncthreads();

    const float csw2 = (0.0625f / (float)SEQ) * 1.4426950408889634f;
    int srcA4 = ((((rg & 1) << 5) + cl) << 2);
    int srcB4 = srcA4 + 64;
    bool hi2  = (rg >= 2);

    for (int qt = 0; qt < 3; ++qt) {
        int qbase = wave * 48 + qt * 16;
        int sq = qbase + cl;
        bf16x8 aq = {};
        if (sq < SEQ)
            aq = *reinterpret_cast<const bf16x8*>(&Qb[base + (size_t)sq * EMB + rg * 8]);
        float sf = (float)sq;

        f32x4 olo = {0.f, 0.f, 0.f, 0.f}, ohi = {0.f, 0.f, 0.f, 0.f};
        float lrow = 0.f;

#pragma unroll
        for (int blk = 0; blk < 6; ++blk) {
            f32x4 s1, s2;
            {
                int t = blk * 32 + cl;
                int kr = t >> 1;
                int kph = (((t & 1) * 4 + rg) ^ (kr & 7));
                bf16x8 kf = *reinterpret_cast<const bf16x8*>(&K2[kr][kph * 8]);
                s1 = __builtin_amdgcn_mfma_f32_16x16x32_bf16(
                    kf, aq, (f32x4){0.f, 0.f, 0.f, 0.f}, 0, 0, 0);
            }
            {
                int t = blk * 32 + 16 + cl;
                int kr = t >> 1;
                int kph = (((t & 1) * 4 + rg) ^ (kr & 7));
                bf16x8 kf = *reinterpret_cast<const bf16x8*>(&K2[kr][kph * 8]);
                s2 = __builtin_amdgcn_mfma_f32_16x16x32_bf16(
                    kf, aq, (f32x4){0.f, 0.f, 0.f, 0.f}, 0, 0, 0);
            }

            int tb1 = blk * 32 + rg * 4;
            int tb2 = tb1 + 16;
            float p1[4], p2[4];
#pragma unroll
            for (int j = 0; j < 4; ++j) {
                p1[j] = exp2f(s1[j] * (fabsf(sf - (float)(tb1 + j)) * csw2));
                p2[j] = exp2f(s2[j] * (fabsf(sf - (float)(tb2 + j)) * csw2));
            }
            if (blk == 5) {
#pragma unroll
                for (int j = 0; j < 4; ++j)
                    if (tb2 + j >= SEQ) p2[j] = 0.f;
            }
            lrow += (p1[0] + p1[1]) + (p1[2] + p1[3])
                  + (p2[0] + p2[1]) + (p2[2] + p2[3]);

            int w10 = (int)cvt_pk_bf16(p1[0], p1[1]);
            int w11 = (int)cvt_pk_bf16(p1[2], p1[3]);
            int w20 = (int)cvt_pk_bf16(p2[0], p2[1]);
            int w21 = (int)cvt_pk_bf16(p2[2], p2[3]);
            int d0a = __builtin_amdgcn_ds_bpermute(srcA4, w10);
            int d0b = __builtin_amdgcn_ds_bpermute(srcA4, w20);
            int d1a = __builtin_amdgcn_ds_bpermute(srcA4, w11);
            int d1b = __builtin_amdgcn_ds_bpermute(srcA4, w21);
            int d2a = __builtin_amdgcn_ds_bpermute(srcB4, w10);
            int d2b = __builtin_amdgcn_ds_bpermute(srcB4, w20);
            int d3a = __builtin_amdgcn_ds_bpermute(srcB4, w11);
            int d3b = __builtin_amdgcn_ds_bpermute(srcB4, w21);
            uint4 pw;
            pw.x = (unsigned)(hi2 ? d0b : d0a);
            pw.y = (unsigned)(hi2 ? d1b : d1a);
            pw.z = (unsigned)(hi2 ? d2b : d2a);
            pw.w = (unsigned)(hi2 ? d3b : d3a);
            bf16x8 pfrag = *reinterpret_cast<bf16x8*>(&pw);

            bf16x8 vlo = *reinterpret_cast<const bf16x8*>(&Vt[cl][blk * 32 + rg * 8]);
            bf16x8 vhi = *reinterpret_cast<const bf16x8*>(&Vt[cl + 16][blk * 32 + rg * 8]);
            olo = __builtin_amdgcn_mfma_f32_16x16x32_bf16(vlo, pfrag, olo, 0, 0, 0);
            ohi = __builtin_amdgcn_mfma_f32_16x16x32_bf16(vhi, pfrag, ohi, 0, 0, 0);
        }

        lrow += __shfl_xor(lrow, 16);
        lrow += __shfl_xor(lrow, 32);

        if (sq < SEQ) {
            float rl = 1.0f / lrow;
            __hip_bfloat16* op = &O[base + (size_t)sq * EMB];
            uint2 wlo, whi;
            wlo.x = cvt_pk_bf16(olo[0] * rl, olo[1] * rl);
            wlo.y = cvt_pk_bf16(olo[2] * rl, olo[3] * rl);
            whi.x = cvt_pk_bf16(ohi[0] * rl, ohi[1] * rl);
            whi.y = cvt_pk_bf16(ohi[2] * rl, ohi[3] * rl);
            *reinterpret_cast<uint2*>(&op[rg * 4])      = wlo;
            *reinterpret_cast<uint2*>(&op[16 + rg * 4]) = whi;
        }
    }
}

// ---------------- row LayerNorm + PE: wave-per-row, 4 rows/block, bf16 io
__global__ __launch_bounds__(256) void ln_pe4_kernel(
    const __hip_bfloat16* __restrict__ X, const float* __restrict__ g,
    const float* __restrict__ bb, const float* __restrict__ pe,
    __hip_bfloat16* __restrict__ Xb, int M)
{
    int r = blockIdx.x * 4 + (threadIdx.x >> 6);
    if (r >= M) return;
    int lane = threadIdx.x & 63;
    int s = r % SEQ;
    int c0 = lane * 4;

    uint2 raw = *reinterpret_cast<const uint2*>(&X[(size_t)r * EMB + c0]);
    float v[4];
    v[0] = __uint_as_float((raw.x & 0xffffu) << 16);
    v[1] = __uint_as_float(raw.x & 0xffff0000u);
    v[2] = __uint_as_float((raw.y & 0xffffu) << 16);
    v[3] = __uint_as_float(raw.y & 0xffff0000u);

    float sum = v[0] + v[1] + v[2] + v[3];
    float sq  = v[0]*v[0] + v[1]*v[1] + v[2]*v[2] + v[3]*v[3];
#pragma unroll
    for (int off = 32; off > 0; off >>= 1) {
        sum += __shfl_xor(sum, off);
        sq  += __shfl_xor(sq,  off);
    }
    float mu  = sum * (1.0f / EMB);
    float var = sq * (1.0f / EMB) - mu * mu;
    float is  = rsqrtf(var + EPSV);

    float4 gv = *reinterpret_cast<const float4*>(&g[c0]);
    float4 bv = *reinterpret_cast<const float4*>(&bb[c0]);
    float4 pv = *reinterpret_cast<const float4*>(&pe[s * EMB + c0]);
    float y0 = (v[0] - mu) * is * gv.x + bv.x + pv.x;
    float y1 = (v[1] - mu) * is * gv.y + bv.y + pv.y;
    float y2 = (v[2] - mu) * is * gv.z + bv.z + pv.z;
    float y3 = (v[3] - mu) * is * gv.w + bv.w + pv.w;

    uint2 o;
    o.x = cvt_pk_bf16(y0, y1);
    o.y = cvt_pk_bf16(y2, y3);
    *reinterpret_cast<uint2*>(&Xb[(size_t)r * EMB + c0]) = o;
}

// ------- fused: LN(lnA2) -> LN(ln2) -> mean-pool over SEQ -> FC[10], 8 waves
__global__ __launch_bounds__(512) void lnfc_kernel(
    const __hip_bfloat16* __restrict__ X,
    const float* __restrict__ g1, const float* __restrict__ b1,
    const float* __restrict__ g2, const float* __restrict__ b2,
    const float* __restrict__ ow, const float* __restrict__ ob,
    float* __restrict__ out)
{
    int b    = blockIdx.x;
    int tid  = threadIdx.x;
    int wave = tid >> 6, lane = tid & 63;

    float g1v[4], b1v[4], g2v[4], b2v[4], pooled[4];
#pragma unroll
    for (int j = 0; j < 4; ++j) {
        int c = lane + 64 * j;
        g1v[j] = g1[c]; b1v[j] = b1[c];
        g2v[j] = g2[c]; b2v[j] = b2[c];
        pooled[j] = 0.f;
    }

    for (int s = wave; s < SEQ; s += 8) {
        const __hip_bfloat16* row = &X[((size_t)b * SEQ + s) * EMB];
        float v[4];
#pragma unroll
        for (int j = 0; j < 4; ++j) v[j] = __bfloat162float(row[lane + 64 * j]);

        float sum = v[0] + v[1] + v[2] + v[3];
        float sq  = v[0]*v[0] + v[1]*v[1] + v[2]*v[2] + v[3]*v[3];
#pragma unroll
        for (int off = 32; off > 0; off >>= 1) {
            sum += __shfl_xor(sum, off);
            sq  += __shfl_xor(sq,  off);
        }
        float mu  = sum * (1.0f / EMB);
        float var = sq * (1.0f / EMB) - mu * mu;
        float is  = rsqrtf(var + EPSV);
        float y[4];
#pragma unroll
        for (int j = 0; j < 4; ++j) y[j] = (v[j] - mu) * is * g1v[j] + b1v[j];

        sum = y[0] + y[1] + y[2] + y[3];
        sq  = y[0]*y[0] + y[1]*y[1] + y[2]*y[2] + y[3]*y[3];
#pragma unroll
        for (int off = 32; off > 0; off >>= 1) {
            sum += __shfl_xor(sum, off);
            sq  += __shfl_xor(sq,  off);
        }
        mu  = sum * (1.0f / EMB);
        var = sq * (1.0f / EMB) - mu * mu;
        is  = rsqrtf(var + EPSV);
#pragma unroll
        for (int j = 0; j < 4; ++j) pooled[j] += (y[j] - mu) * is * g2v[j] + b2v[j];
    }

    __shared__ float pp[8][EMB];
#pragma unroll
    for (int j = 0; j < 4; ++j) pp[wave][lane + 64 * j] = pooled[j];
    __syncthreads();
    __shared__ float pool[EMB];
    if (tid < EMB) {
        float pl = 0.f;
#pragma unroll
        for (int w = 0; w < 8; ++w) pl += pp[w][tid];
        pool[tid] = pl * (1.0f / (float)SEQ);
    }
    __syncthreads();
    if (tid < 10) {
        float o = ob[tid];
        for (int k = 0; k < EMB; ++k) o += pool[k] * ow[tid * EMB + k];
        out[b * 10 + tid] = o;
    }
}

// ---------------------------------------------------------------- launch
extern "C" void kernel_launch(void* const* d_in, const int* in_sizes, int n_in,
                              void* d_out, int out_size, void* d_ws, size_t ws_size,
                              hipStream_t stream)
{
    const float* x      = (const float*)d_in[0];
    const float* conv_w = (const float*)d_in[1];
    const float* conv_b = (const float*)d_in[2];
    const float* bn_g   = (const float*)d_in[3];
    const float* bn_b   = (const float*)d_in[4];
    const float* bn_m   = (const float*)d_in[5];
    const float* bn_v   = (const float*)d_in[6];
    const float* wq1    = (const float*)d_in[7];
    const float* wk1    = (const float*)d_in[8];
    const float* wv1    = (const float*)d_in[9];
    const float* lnA1_g = (const float*)d_in[10];
    const float* lnA1_b = (const float*)d_in[11];
    const float* wq2    = (const float*)d_in[12];
    const float* wk2    = (const float*)d_in[13];
    const float* wv2    = (const float*)d_in[14];
    const float* lnA2_g = (const float*)d_in[15];
    const float* lnA2_b = (const float*)d_in[16];
    const float* ln2_g  = (const float*)d_in[17];
    const float* ln2_b  = (const float*)d_in[18];
    const float* out_w  = (const float*)d_in[19];
    const float* out_b  = (const float*)d_in[20];
    float* out = (float*)d_out;

    const size_t peN = (size_t)SEQ * EMB;
    const size_t wN  = (size_t)EMB * EMB;
    const size_t foldN = 8 * EMB + EMB;           // wt[8][256] + bp[256]

    int chunk = B_TOT;
    while (chunk > 1) {
        size_t M    = (size_t)chunk * SEQ;
        size_t Mpad = (M + 127) / 128 * 128;
        size_t need = (peN + foldN) * 4 + 6 * wN * 2 + (Mpad + 4 * M) * EMB * 2;
        if (need <= ws_size) break;
        chunk >>= 1;
    }
    size_t M    = (size_t)chunk * SEQ;
    size_t Mpad = (M + 127) / 128 * 128;

    float*          pe = (float*)d_ws;
    float*          wt = pe + peN;
    float*          bp = wt + 8 * EMB;
    __hip_bfloat16* Wb = (__hip_bfloat16*)(bp + EMB);
    __hip_bfloat16* Xb = Wb + 6 * wN;
    __hip_bfloat16* Ob = Xb + Mpad * EMB;
    __hip_bfloat16* Qb = Ob + M * EMB;
    __hip_bfloat16* Kb = Qb + M * EMB;
    __hip_bfloat16* Vb = Kb + M * EMB;

    pe_kernel<<<(SEQ * EMB + 255) / 256, 256, 0, stream>>>(pe);
    fold_conv_kernel<<<1, 256, 0, stream>>>(conv_w, conv_b, bn_g, bn_b, bn_m, bn_v, wt, bp);
    {
        dim3 cg((unsigned)(wN / 1024), 6);
        cvt6_kernel<<<cg, 256, 0, stream>>>(wq1, wk1, wv1, wq2, wk2, wv2, Wb, (int)wN);
    }

    for (int b0 = 0; b0 < B_TOT; b0 += chunk) {
        int Bc = chunk;
        int Mi = Bc * SEQ;
        dim3 ggrid((unsigned)(Mpad / 128), 6);

        embed_kernel<<<(Mi + 15) / 16, 256, 0, stream>>>(
            x + (size_t)b0 * LIN, wt, bp, pe, Xb, Mi);

        // --- attention block 1 ---
        gemm_qkv_mfma<<<ggrid, 256, 0, stream>>>(Xb, Wb, Qb, Kb, Vb, Mi);
        attn_mfma_kernel<<<Bc * HEADS, 256, 0, stream>>>(Qb, Kb, Vb, Ob);
        ln_pe4_kernel<<<(Mi + 3) / 4, 256, 0, stream>>>(Ob, lnA1_g, lnA1_b, pe, Xb, Mi);

        // --- attention block 2 ---
        gemm_qkv_mfma<<<ggrid, 256, 0, stream>>>(Xb, Wb + 3 * wN, Qb, Kb, Vb, Mi);
        attn_mfma_kernel<<<Bc * HEADS, 256, 0, stream>>>(Qb, Kb, Vb, Ob);
        lnfc_kernel<<<Bc, 512, 0, stream>>>(Ob, lnA2_g, lnA2_b, ln2_g, ln2_b,
                                            out_w, out_b, out + (size_t)b0 * 10);
    }
}

// Round 13
// 344.429 us; speedup vs baseline: 1.2919x; 1.0473x over previous
//
#include <hip/hip_runtime.h>
#include <hip/hip_bf16.h>
#include <math.h>

#define B_TOT 512
#define SEQ   179
#define EMB   256
#define HEADS 8
#define HD    32
#define LIN   720
#define EPSV  1e-5f

typedef __attribute__((ext_vector_type(8))) short bf16x8;
typedef __attribute__((ext_vector_type(4))) short bf16x4;
typedef __attribute__((ext_vector_type(4))) float f32x4;

__device__ __forceinline__ unsigned cvt_pk_bf16(float lo, float hi) {
    unsigned r;
    asm("v_cvt_pk_bf16_f32 %0, %1, %2" : "=v"(r) : "v"(lo), "v"(hi));
    return r;
}

__device__ __forceinline__ f32x4 mfma16x16x16(bf16x4 a, bf16x4 b, f32x4 c) {
#if __has_builtin(__builtin_amdgcn_mfma_f32_16x16x16bf16_1k)
    return __builtin_amdgcn_mfma_f32_16x16x16bf16_1k(a, b, c, 0, 0, 0);
#else
    asm volatile("v_mfma_f32_16x16x16_bf16 %0, %1, %2, %0"
                 : "+v"(c) : "v"(a), "v"(b));
    return c;
#endif
}

// ---------------------------------------------------------------- PE table
__global__ void pe_kernel(float* __restrict__ pe) {
    int idx = blockIdx.x * 256 + threadIdx.x;
    if (idx >= SEQ * EMB) return;
    int s = idx / EMB, e = idx % EMB;
    int i = e >> 1;
    float dv  = expf((float)(2 * i) * (-9.210340371976184f / (float)EMB));
    float ang = (float)s * dv * ((float)EMB / (float)SEQ);
    pe[idx] = (e & 1) ? cosf(ang) : sinf(ang);
}

// --------------- one-time: fold BN into conv weights; wt transposed [8][256]
__global__ void fold_conv_kernel(const float* __restrict__ cw, const float* __restrict__ cb,
                                 const float* __restrict__ g, const float* __restrict__ bb,
                                 const float* __restrict__ mean, const float* __restrict__ var,
                                 float* __restrict__ wt, float* __restrict__ bp) {
    int e = threadIdx.x;                  // 256 threads, 1 block
    float is = g[e] * rsqrtf(var[e] + EPSV);
#pragma unroll
    for (int j = 0; j < 8; ++j) wt[j * EMB + e] = cw[e * 8 + j] * is;
    bp[e] = (cb[e] - mean[e]) * is + bb[e];
}

// ------------------------------------- f32 -> bf16 convert, 6 weights at once
__global__ void cvt6_kernel(const float* __restrict__ s0, const float* __restrict__ s1,
                            const float* __restrict__ s2, const float* __restrict__ s3,
                            const float* __restrict__ s4, const float* __restrict__ s5,
                            __hip_bfloat16* __restrict__ dst, int n) {
    int w = blockIdx.y;
    const float* src = (w == 0) ? s0 : (w == 1) ? s1 : (w == 2) ? s2
                     : (w == 3) ? s3 : (w == 4) ? s4 : s5;
    __hip_bfloat16* d = dst + (size_t)w * n;
    int i = (blockIdx.x * 256 + threadIdx.x) * 4;
    if (i < n) {
        float4 v = *reinterpret_cast<const float4*>(&src[i]);
        d[i + 0] = __float2bfloat16(v.x);
        d[i + 1] = __float2bfloat16(v.y);
        d[i + 2] = __float2bfloat16(v.z);
        d[i + 3] = __float2bfloat16(v.w);
    }
}

// ------------ embed v3: conv(stride4,K8,BN-folded) + ReLU + PE -> bf16
__global__ __launch_bounds__(256) void embed_kernel(
    const float* __restrict__ x, const float* __restrict__ wt,
    const float* __restrict__ bp, const float* __restrict__ pe,
    __hip_bfloat16* __restrict__ Xb, int M)
{
    int lane = threadIdx.x & 63;
    int wv   = threadIdx.x >> 6;
    int e0   = lane * 4;

    float wreg[8][4];
#pragma unroll
    for (int j = 0; j < 8; ++j)
        *reinterpret_cast<float4*>(wreg[j]) = *reinterpret_cast<const float4*>(&wt[j * EMB + e0]);
    float4 bpv = *reinterpret_cast<const float4*>(&bp[e0]);

    int r0 = blockIdx.x * 16 + wv * 4;
#pragma unroll
    for (int rr = 0; rr < 4; ++rr) {
        int r = r0 + rr;
        if (r >= M) return;               // rows ascend; safe early-out
        int b = r / SEQ, s = r - b * SEQ;
        const float* xr = &x[(size_t)b * LIN + s * 4];
        float4 xa = *reinterpret_cast<const float4*>(xr);
        float4 xc = *reinterpret_cast<const float4*>(xr + 4);
        float xi[8] = {xa.x, xa.y, xa.z, xa.w, xc.x, xc.y, xc.z, xc.w};
        float4 pv = *reinterpret_cast<const float4*>(&pe[s * EMB + e0]);
        const float* bpa = reinterpret_cast<const float*>(&bpv);
        const float* pva = reinterpret_cast<const float*>(&pv);
        float y[4];
#pragma unroll
        for (int c = 0; c < 4; ++c) {
            float acc = bpa[c];
#pragma unroll
            for (int j = 0; j < 8; ++j) acc += xi[j] * wreg[j][c];
            y[c] = fmaxf(acc, 0.f) + pva[c];
        }
        uint2 o;
        o.x = cvt_pk_bf16(y[0], y[1]);
        o.y = cvt_pk_bf16(y[2], y[3]);
        *reinterpret_cast<uint2*>(&Xb[(size_t)r * EMB + e0]) = o;
    }
}

// ---------------- MFMA bf16 GEMM: C[m,n] = sum_k A[m,k] * W[n,k], C in bf16
// grid = (6, Mtiles): A-sharing blocks dispatch-adjacent -> A from L2/L3.
__global__ __launch_bounds__(256) void gemm_qkv_mfma(
    const __hip_bfloat16* __restrict__ A,    // [Mpad][256]
    const __hip_bfloat16* __restrict__ Wset, // [3][256][256]
    __hip_bfloat16* __restrict__ Q, __hip_bfloat16* __restrict__ K,
    __hip_bfloat16* __restrict__ V, int M)
{
    int by = blockIdx.x;                       // 0..5
    int wsel = by >> 1;
    const __hip_bfloat16* W = Wset + (size_t)wsel * EMB * EMB;
    __hip_bfloat16* C = (wsel == 0) ? Q : (wsel == 1 ? K : V);
    int nbase = (by & 1) * 128;
    int mbase = blockIdx.y * 128;

    __shared__ __hip_bfloat16 As[128][64];
    __shared__ __hip_bfloat16 Bs[128][64];

    int tid  = threadIdx.x;
    int wave = tid >> 6, lane = tid & 63;
    int wr = wave >> 1, wc = wave & 1;

    int r0   = tid >> 3;
    int srcs = (tid & 7) ^ (r0 & 7);
    const __hip_bfloat16* gA = A + (size_t)(mbase + r0) * EMB + srcs * 8;
    const __hip_bfloat16* gB = W + (size_t)(nbase + r0) * EMB + srcs * 8;

    f32x4 acc[4][4];
#pragma unroll
    for (int i = 0; i < 4; ++i)
#pragma unroll
        for (int j = 0; j < 4; ++j) acc[i][j] = (f32x4){0.f, 0.f, 0.f, 0.f};

    for (int kt = 0; kt < EMB; kt += 64) {
        if (kt) __syncthreads();
#pragma unroll
        for (int i = 0; i < 4; ++i) {
            __hip_bfloat16* l = &As[0][0] + i * 2048 + tid * 8;
            __builtin_amdgcn_global_load_lds(
                (const __attribute__((address_space(1))) void*)(gA + (size_t)i * 32 * EMB + kt),
                (__attribute__((address_space(3))) void*)l, 16, 0, 0);
        }
#pragma unroll
        for (int i = 0; i < 4; ++i) {
            __hip_bfloat16* l = &Bs[0][0] + i * 2048 + tid * 8;
            __builtin_amdgcn_global_load_lds(
                (const __attribute__((address_space(1))) void*)(gB + (size_t)i * 32 * EMB + kt),
                (__attribute__((address_space(3))) void*)l, 16, 0, 0);
        }
        asm volatile("s_waitcnt vmcnt(0)" ::: "memory");
        __syncthreads();

#pragma unroll
        for (int kk = 0; kk < 2; ++kk) {
            bf16x8 af[4], bfr[4];
            int sg = kk * 4 + (lane >> 4);
#pragma unroll
            for (int mi = 0; mi < 4; ++mi) {
                int row = wr * 64 + mi * 16 + (lane & 15);
                int sl  = sg ^ (row & 7);
                af[mi] = *reinterpret_cast<const bf16x8*>(&As[row][sl * 8]);
            }
#pragma unroll
            for (int ni = 0; ni < 4; ++ni) {
                int row = wc * 64 + ni * 16 + (lane & 15);
                int sl  = sg ^ (row & 7);
                bfr[ni] = *reinterpret_cast<const bf16x8*>(&Bs[row][sl * 8]);
            }
#pragma unroll
            for (int mi = 0; mi < 4; ++mi)
#pragma unroll
                for (int ni = 0; ni < 4; ++ni)
                    acc[mi][ni] = __builtin_amdgcn_mfma_f32_16x16x32_bf16(
                        af[mi], bfr[ni], acc[mi][ni], 0, 0, 0);
        }
    }

    int rg = lane >> 4, cli = lane & 15;
#pragma unroll
    for (int mi = 0; mi < 4; ++mi)
#pragma unroll
        for (int j = 0; j < 4; ++j) {
            int m = mbase + wr * 64 + mi * 16 + rg * 4 + j;
            if (m < M) {
#pragma unroll
                for (int ni = 0; ni < 4; ++ni)
                    C[(size_t)m * EMB + nbase + wc * 64 + ni * 16 + cli] =
                        __float2bfloat16(acc[mi][ni][j]);
            }
        }
}

// ---------------- MFMA flash attention v5: PV via 16x16x16 MFMA whose
// B-operand k-grouping (rg*4+j) matches QK's C-layout directly ->
// no bpermute, no regroup. q lane-local end to end.
__global__ __launch_bounds__(256) void attn_mfma_kernel(
    const __hip_bfloat16* __restrict__ Qb, const __hip_bfloat16* __restrict__ Kb,
    const __hip_bfloat16* __restrict__ Vb, __hip_bfloat16* __restrict__ O)
{
    int bh = blockIdx.x;
    int b = bh >> 3, h = bh & 7;
    const size_t base = (size_t)b * SEQ * EMB + (size_t)h * HD;

    __shared__ short K2[96][64];          // 12288 B, XOR-swizzled
    __shared__ short Vt[32][212];         // 13568 B, stride 212 -> <=2-way

    int tid  = threadIdx.x;
    int wave = tid >> 6, lane = tid & 63;
    int cl = lane & 15, rg = lane >> 4;

    // ---- stage K (swizzled b128 writes)
    for (int u = tid; u < 192 * 4; u += 256) {
        int t = u >> 2, d0 = (u & 3) << 3;
        uint4 kv = make_uint4(0, 0, 0, 0);
        if (t < SEQ) kv = *reinterpret_cast<const uint4*>(&Kb[base + (size_t)t * EMB + d0]);
        int krow = t >> 1;
        int kphy = (((t & 1) * 4 + (d0 >> 3)) ^ (krow & 7));
        *reinterpret_cast<uint4*>(&K2[krow][kphy * 8]) = kv;
    }
    // ---- stage V^T: register quad-transpose, b64 writes
    if (tid < 192) {
        int tq = tid >> 2, d0 = (tid & 3) << 3;
        int t0 = tq * 4;
        uint4 r0 = make_uint4(0,0,0,0), r1 = r0, r2 = r0, r3 = r0;
        if (t0 + 0 < SEQ) r0 = *reinterpret_cast<const uint4*>(&Vb[base + (size_t)(t0+0)*EMB + d0]);
        if (t0 + 1 < SEQ) r1 = *reinterpret_cast<const uint4*>(&Vb[base + (size_t)(t0+1)*EMB + d0]);
        if (t0 + 2 < SEQ) r2 = *reinterpret_cast<const uint4*>(&Vb[base + (size_t)(t0+2)*EMB + d0]);
        if (t0 + 3 < SEQ) r3 = *reinterpret_cast<const uint4*>(&Vb[base + (size_t)(t0+3)*EMB + d0]);
        const unsigned* q0 = reinterpret_cast<const unsigned*>(&r0);
        const unsigned* q1 = reinterpret_cast<const unsigned*>(&r1);
        const unsigned* q2 = reinterpret_cast<const unsigned*>(&r2);
        const unsigned* q3 = reinterpret_cast<const unsigned*>(&r3);
#pragma unroll
        for (int k = 0; k < 8; ++k) {
            int dw = k >> 1, sh = (k & 1) * 16;
            unsigned a0 = (q0[dw] >> sh) & 0xffffu;
            unsigned a1 = (q1[dw] >> sh) & 0xffffu;
            unsigned a2 = (q2[dw] >> sh) & 0xffffu;
            unsigned a3 = (q3[dw] >> sh) & 0xffffu;
            uint2 w;
            w.x = a0 | (a1 << 16);
            w.y = a2 | (a3 << 16);
            *reinterpret_cast<uint2*>(&Vt[d0 + k][t0]) = w;
        }
    }
    __syncthreads();

    const float csw2 = (0.0625f / (float)SEQ) * 1.4426950408889634f;

    for (int qt = 0; qt < 3; ++qt) {
        int qbase = wave * 48 + qt * 16;
        int sq = qbase + cl;
        bf16x8 aq = {};
        if (sq < SEQ)
            aq = *reinterpret_cast<const bf16x8*>(&Qb[base + (size_t)sq * EMB + rg * 8]);
        float sf = (float)sq;

        f32x4 olo = {0.f, 0.f, 0.f, 0.f}, ohi = {0.f, 0.f, 0.f, 0.f};
        float lrow = 0.f;

#pragma unroll
        for (int blk = 0; blk < 6; ++blk) {
            // ---- K^T Q for two 16-t tiles (C: lane q=cl, t=rg*4+j)
            f32x4 s1, s2;
            {
                int t = blk * 32 + cl;
                int kr = t >> 1;
                int kph = (((t & 1) * 4 + rg) ^ (kr & 7));
                bf16x8 kf = *reinterpret_cast<const bf16x8*>(&K2[kr][kph * 8]);
                s1 = __builtin_amdgcn_mfma_f32_16x16x32_bf16(
                    kf, aq, (f32x4){0.f, 0.f, 0.f, 0.f}, 0, 0, 0);
            }
            {
                int t = blk * 32 + 16 + cl;
                int kr = t >> 1;
                int kph = (((t & 1) * 4 + rg) ^ (kr & 7));
                bf16x8 kf = *reinterpret_cast<const bf16x8*>(&K2[kr][kph * 8]);
                s2 = __builtin_amdgcn_mfma_f32_16x16x32_bf16(
                    kf, aq, (f32x4){0.f, 0.f, 0.f, 0.f}, 0, 0, 0);
            }

            // ---- weight + exp (no-max softmax: |logit| <= ~0.2)
            int tb1 = blk * 32 + rg * 4;
            int tb2 = tb1 + 16;
            float p1[4], p2[4];
#pragma unroll
            for (int j = 0; j < 4; ++j) {
                p1[j] = exp2f(s1[j] * (fabsf(sf - (float)(tb1 + j)) * csw2));
                p2[j] = exp2f(s2[j] * (fabsf(sf - (float)(tb2 + j)) * csw2));
            }
            if (blk == 5) {                       // only tile2 holds t >= SEQ
#pragma unroll
                for (int j = 0; j < 4; ++j)
                    if (tb2 + j >= SEQ) p2[j] = 0.f;
            }
            lrow += (p1[0] + p1[1]) + (p1[2] + p1[3])
                  + (p2[0] + p2[1]) + (p2[2] + p2[3]);

            // ---- P fragments: cvt_pk pairs ARE the 16x16x16 B-operand
            uint2 u1, u2;
            u1.x = cvt_pk_bf16(p1[0], p1[1]);
            u1.y = cvt_pk_bf16(p1[2], p1[3]);
            u2.x = cvt_pk_bf16(p2[0], p2[1]);
            u2.y = cvt_pk_bf16(p2[2], p2[3]);
            bf16x4 pf1 = *reinterpret_cast<bf16x4*>(&u1);
            bf16x4 pf2 = *reinterpret_cast<bf16x4*>(&u2);

            // ---- PV: O^T[d][q] += V^T[d][t] * P^T[t][q], two 16-t tiles
            int tA = blk * 32 + rg * 4;
            bf16x4 v1lo = *reinterpret_cast<const bf16x4*>(&Vt[cl][tA]);
            bf16x4 v2lo = *reinterpret_cast<const bf16x4*>(&Vt[cl][tA + 16]);
            bf16x4 v1hi = *reinterpret_cast<const bf16x4*>(&Vt[cl + 16][tA]);
            bf16x4 v2hi = *reinterpret_cast<const bf16x4*>(&Vt[cl + 16][tA + 16]);
            olo = mfma16x16x16(v1lo, pf1, olo);
            olo = mfma16x16x16(v2lo, pf2, olo);
            ohi = mfma16x16x16(v1hi, pf1, ohi);
            ohi = mfma16x16x16(v2hi, pf2, ohi);
        }

        // ---- row sum: q=cl lane-local; reduce over the 4 rg groups
        lrow += __shfl_xor(lrow, 16);
        lrow += __shfl_xor(lrow, 32);

        // ---- store: lane owns O[q=sq][d = rg*4..+3 and +16], b64 each
        if (sq < SEQ) {
            float rl = 1.0f / lrow;
            __hip_bfloat16* op = &O[base + (size_t)sq * EMB];
            uint2 wlo, whi;
            wlo.x = cvt_pk_bf16(olo[0] * rl, olo[1] * rl);
            wlo.y = cvt_pk_bf16(olo[2] * rl, olo[3] * rl);
            whi.x = cvt_pk_bf16(ohi[0] * rl, ohi[1] * rl);
            whi.y = cvt_pk_bf16(ohi[2] * rl, ohi[3] * rl);
            *reinterpret_cast<uint2*>(&op[rg * 4])      = wlo;
            *reinterpret_cast<uint2*>(&op[16 + rg * 4]) = whi;
        }
    }
}

// ---------------- row LayerNorm + PE: wave-per-row, 4 rows/block, bf16 io
__global__ __launch_bounds__(256) void ln_pe4_kernel(
    const __hip_bfloat16* __restrict__ X, const float* __restrict__ g,
    const float* __restrict__ bb, const float* __restrict__ pe,
    __hip_bfloat16* __restrict__ Xb, int M)
{
    int r = blockIdx.x * 4 + (threadIdx.x >> 6);
    if (r >= M) return;
    int lane = threadIdx.x & 63;
    int s = r % SEQ;
    int c0 = lane * 4;

    uint2 raw = *reinterpret_cast<const uint2*>(&X[(size_t)r * EMB + c0]);
    float v[4];
    v[0] = __uint_as_float((raw.x & 0xffffu) << 16);
    v[1] = __uint_as_float(raw.x & 0xffff0000u);
    v[2] = __uint_as_float((raw.y & 0xffffu) << 16);
    v[3] = __uint_as_float(raw.y & 0xffff0000u);

    float sum = v[0] + v[1] + v[2] + v[3];
    float sq  = v[0]*v[0] + v[1]*v[1] + v[2]*v[2] + v[3]*v[3];
#pragma unroll
    for (int off = 32; off > 0; off >>= 1) {
        sum += __shfl_xor(sum, off);
        sq  += __shfl_xor(sq,  off);
    }
    float mu  = sum * (1.0f / EMB);
    float var = sq * (1.0f / EMB) - mu * mu;
    float is  = rsqrtf(var + EPSV);

    float4 gv = *reinterpret_cast<const float4*>(&g[c0]);
    float4 bv = *reinterpret_cast<const float4*>(&bb[c0]);
    float4 pv = *reinterpret_cast<const float4*>(&pe[s * EMB + c0]);
    float y0 = (v[0] - mu) * is * gv.x + bv.x + pv.x;
    float y1 = (v[1] - mu) * is * gv.y + bv.y + pv.y;
    float y2 = (v[2] - mu) * is * gv.z + bv.z + pv.z;
    float y3 = (v[3] - mu) * is * gv.w + bv.w + pv.w;

    uint2 o;
    o.x = cvt_pk_bf16(y0, y1);
    o.y = cvt_pk_bf16(y2, y3);
    *reinterpret_cast<uint2*>(&Xb[(size_t)r * EMB + c0]) = o;
}

// ------- fused: LN(lnA2) -> LN(ln2) -> mean-pool over SEQ -> FC[10], 8 waves
__global__ __launch_bounds__(512) void lnfc_kernel(
    const __hip_bfloat16* __restrict__ X,
    const float* __restrict__ g1, const float* __restrict__ b1,
    const float* __restrict__ g2, const float* __restrict__ b2,
    const float* __restrict__ ow, const float* __restrict__ ob,
    float* __restrict__ out)
{
    int b    = blockIdx.x;
    int tid  = threadIdx.x;
    int wave = tid >> 6, lane = tid & 63;

    float g1v[4], b1v[4], g2v[4], b2v[4], pooled[4];
#pragma unroll
    for (int j = 0; j < 4; ++j) {
        int c = lane + 64 * j;
        g1v[j] = g1[c]; b1v[j] = b1[c];
        g2v[j] = g2[c]; b2v[j] = b2[c];
        pooled[j] = 0.f;
    }

    for (int s = wave; s < SEQ; s += 8) {
        const __hip_bfloat16* row = &X[((size_t)b * SEQ + s) * EMB];
        float v[4];
#pragma unroll
        for (int j = 0; j < 4; ++j) v[j] = __bfloat162float(row[lane + 64 * j]);

        float sum = v[0] + v[1] + v[2] + v[3];
        float sq  = v[0]*v[0] + v[1]*v[1] + v[2]*v[2] + v[3]*v[3];
#pragma unroll
        for (int off = 32; off > 0; off >>= 1) {
            sum += __shfl_xor(sum, off);
            sq  += __shfl_xor(sq,  off);
        }
        float mu  = sum * (1.0f / EMB);
        float var = sq * (1.0f / EMB) - mu * mu;
        float is  = rsqrtf(var + EPSV);
        float y[4];
#pragma unroll
        for (int j = 0; j < 4; ++j) y[j] = (v[j] - mu) * is * g1v[j] + b1v[j];

        sum = y[0] + y[1] + y[2] + y[3];
        sq  = y[0]*y[0] + y[1]*y[1] + y[2]*y[2] + y[3]*y[3];
#pragma unroll
        for (int off = 32; off > 0; off >>= 1) {
            sum += __shfl_xor(sum, off);
            sq  += __shfl_xor(sq,  off);
        }
        mu  = sum * (1.0f / EMB);
        var = sq * (1.0f / EMB) - mu * mu;
        is  = rsqrtf(var + EPSV);
#pragma unroll
        for (int j = 0; j < 4; ++j) pooled[j] += (y[j] - mu) * is * g2v[j] + b2v[j];
    }

    __shared__ float pp[8][EMB];
#pragma unroll
    for (int j = 0; j < 4; ++j) pp[wave][lane + 64 * j] = pooled[j];
    __syncthreads();
    __shared__ float pool[EMB];
    if (tid < EMB) {
        float pl = 0.f;
#pragma unroll
        for (int w = 0; w < 8; ++w) pl += pp[w][tid];
        pool[tid] = pl * (1.0f / (float)SEQ);
    }
    __syncthreads();
    if (tid < 10) {
        float o = ob[tid];
        for (int k = 0; k < EMB; ++k) o += pool[k] * ow[tid * EMB + k];
        out[b * 10 + tid] = o;
    }
}

// ---------------------------------------------------------------- launch
extern "C" void kernel_launch(void* const* d_in, const int* in_sizes, int n_in,
                              void* d_out, int out_size, void* d_ws, size_t ws_size,
                              hipStream_t stream)
{
    const float* x      = (const float*)d_in[0];
    const float* conv_w = (const float*)d_in[1];
    const float* conv_b = (const float*)d_in[2];
    const float* bn_g   = (const float*)d_in[3];
    const float* bn_b   = (const float*)d_in[4];
    const float* bn_m   = (const float*)d_in[5];
    const float* bn_v   = (const float*)d_in[6];
    const float* wq1    = (const float*)d_in[7];
    const float* wk1    = (const float*)d_in[8];
    const float* wv1    = (const float*)d_in[9];
    const float* lnA1_g = (const float*)d_in[10];
    const float* lnA1_b = (const float*)d_in[11];
    const float* wq2    = (const float*)d_in[12];
    const float* wk2    = (const float*)d_in[13];
    const float* wv2    = (const float*)d_in[14];
    const float* lnA2_g = (const float*)d_in[15];
    const float* lnA2_b = (const float*)d_in[16];
    const float* ln2_g  = (const float*)d_in[17];
    const float* ln2_b  = (const float*)d_in[18];
    const float* out_w  = (const float*)d_in[19];
    const float* out_b  = (const float*)d_in[20];
    float* out = (float*)d_out;

    const size_t peN = (size_t)SEQ * EMB;
    const size_t wN  = (size_t)EMB * EMB;
    const size_t foldN = 8 * EMB + EMB;           // wt[8][256] + bp[256]

    int chunk = B_TOT;
    while (chunk > 1) {
        size_t M    = (size_t)chunk * SEQ;
        size_t Mpad = (M + 127) / 128 * 128;
        size_t need = (peN + foldN) * 4 + 6 * wN * 2 + (Mpad + 4 * M) * EMB * 2;
        if (need <= ws_size) break;
        chunk >>= 1;
    }
    size_t M    = (size_t)chunk * SEQ;
    size_t Mpad = (M + 127) / 128 * 128;

    float*          pe = (float*)d_ws;
    float*          wt = pe + peN;
    float*          bp = wt + 8 * EMB;
    __hip_bfloat16* Wb = (__hip_bfloat16*)(bp + EMB);
    __hip_bfloat16* Xb = Wb + 6 * wN;
    __hip_bfloat16* Ob = Xb + Mpad * EMB;
    __hip_bfloat16* Qb = Ob + M * EMB;
    __hip_bfloat16* Kb = Qb + M * EMB;
    __hip_bfloat16* Vb = Kb + M * EMB;

    pe_kernel<<<(SEQ * EMB + 255) / 256, 256, 0, stream>>>(pe);
    fold_conv_kernel<<<1, 256, 0, stream>>>(conv_w, conv_b, bn_g, bn_b, bn_m, bn_v, wt, bp);
    {
        dim3 cg((unsigned)(wN / 1024), 6);
        cvt6_kernel<<<cg, 256, 0, stream>>>(wq1, wk1, wv1, wq2, wk2, wv2, Wb, (int)wN);
    }

    for (int b0 = 0; b0 < B_TOT; b0 += chunk) {
        int Bc = chunk;
        int Mi = Bc * SEQ;
        dim3 ggrid(6, (unsigned)(Mpad / 128));

        embed_kernel<<<(Mi + 15) / 16, 256, 0, stream>>>(
            x + (size_t)b0 * LIN, wt, bp, pe, Xb, Mi);

        // --- attention block 1 ---
        gemm_qkv_mfma<<<ggrid, 256, 0, stream>>>(Xb, Wb, Qb, Kb, Vb, Mi);
        attn_mfma_kernel<<<Bc * HEADS, 256, 0, stream>>>(Qb, Kb, Vb, Ob);
        ln_pe4_kernel<<<(Mi + 3) / 4, 256, 0, stream>>>(Ob, lnA1_g, lnA1_b, pe, Xb, Mi);

        // --- attention block 2 ---
        gemm_qkv_mfma<<<ggrid, 256, 0, stream>>>(Xb, Wb + 3 * wN, Qb, Kb, Vb, Mi);
        attn_mfma_kernel<<<Bc * HEADS, 256, 0, stream>>>(Qb, Kb, Vb, Ob);
        lnfc_kernel<<<Bc, 512, 0, stream>>>(Ob, lnA2_g, lnA2_b, ln2_g, ln2_b,
                                            out_w, out_b, out + (size_t)b0 * 10);
    }
}

// Round 16
// 341.949 us; speedup vs baseline: 1.3013x; 1.0073x over previous
//
#include <hip/hip_runtime.h>
#include <hip/hip_bf16.h>
#include <math.h>

#define B_TOT 512
#define SEQ   179
#define EMB   256
#define HEADS 8
#define HD    32
#define LIN   720
#define EPSV  1e-5f

typedef __attribute__((ext_vector_type(8))) short bf16x8;
typedef __attribute__((ext_vector_type(4))) short bf16x4;
typedef __attribute__((ext_vector_type(4))) float f32x4;

__device__ __forceinline__ unsigned cvt_pk_bf16(float lo, float hi) {
    unsigned r;
    asm("v_cvt_pk_bf16_f32 %0, %1, %2" : "=v"(r) : "v"(lo), "v"(hi));
    return r;
}

__device__ __forceinline__ f32x4 mfma16x16x16(bf16x4 a, bf16x4 b, f32x4 c) {
#if __has_builtin(__builtin_amdgcn_mfma_f32_16x16x16bf16_1k)
    return __builtin_amdgcn_mfma_f32_16x16x16bf16_1k(a, b, c, 0, 0, 0);
#else
    asm volatile("v_mfma_f32_16x16x16_bf16 %0, %1, %2, %0"
                 : "+v"(c) : "v"(a), "v"(b));
    return c;
#endif
}

// ---------------------------------------------------------------- PE table
__global__ void pe_kernel(float* __restrict__ pe) {
    int idx = blockIdx.x * 256 + threadIdx.x;
    if (idx >= SEQ * EMB) return;
    int s = idx / EMB, e = idx % EMB;
    int i = e >> 1;
    float dv  = expf((float)(2 * i) * (-9.210340371976184f / (float)EMB));
    float ang = (float)s * dv * ((float)EMB / (float)SEQ);
    pe[idx] = (e & 1) ? cosf(ang) : sinf(ang);
}

// --------------- one-time: fold BN into conv weights; wt transposed [8][256]
__global__ void fold_conv_kernel(const float* __restrict__ cw, const float* __restrict__ cb,
                                 const float* __restrict__ g, const float* __restrict__ bb,
                                 const float* __restrict__ mean, const float* __restrict__ var,
                                 float* __restrict__ wt, float* __restrict__ bp) {
    int e = threadIdx.x;                  // 256 threads, 1 block
    float is = g[e] * rsqrtf(var[e] + EPSV);
#pragma unroll
    for (int j = 0; j < 8; ++j) wt[j * EMB + e] = cw[e * 8 + j] * is;
    bp[e] = (cb[e] - mean[e]) * is + bb[e];
}

// ------------------------------------- f32 -> bf16 convert, 6 weights at once
__global__ void cvt6_kernel(const float* __restrict__ s0, const float* __restrict__ s1,
                            const float* __restrict__ s2, const float* __restrict__ s3,
                            const float* __restrict__ s4, const float* __restrict__ s5,
                            __hip_bfloat16* __restrict__ dst, int n) {
    int w = blockIdx.y;
    const float* src = (w == 0) ? s0 : (w == 1) ? s1 : (w == 2) ? s2
                     : (w == 3) ? s3 : (w == 4) ? s4 : s5;
    __hip_bfloat16* d = dst + (size_t)w * n;
    int i = (blockIdx.x * 256 + threadIdx.x) * 4;
    if (i < n) {
        float4 v = *reinterpret_cast<const float4*>(&src[i]);
        d[i + 0] = __float2bfloat16(v.x);
        d[i + 1] = __float2bfloat16(v.y);
        d[i + 2] = __float2bfloat16(v.z);
        d[i + 3] = __float2bfloat16(v.w);
    }
}

// ------------ embed v3: conv(stride4,K8,BN-folded) + ReLU + PE -> bf16
__global__ __launch_bounds__(256) void embed_kernel(
    const float* __restrict__ x, const float* __restrict__ wt,
    const float* __restrict__ bp, const float* __restrict__ pe,
    __hip_bfloat16* __restrict__ Xb, int M)
{
    int lane = threadIdx.x & 63;
    int wv   = threadIdx.x >> 6;
    int e0   = lane * 4;

    float wreg[8][4];
#pragma unroll
    for (int j = 0; j < 8; ++j)
        *reinterpret_cast<float4*>(wreg[j]) = *reinterpret_cast<const float4*>(&wt[j * EMB + e0]);
    float4 bpv = *reinterpret_cast<const float4*>(&bp[e0]);

    int r0 = blockIdx.x * 16 + wv * 4;
#pragma unroll
    for (int rr = 0; rr < 4; ++rr) {
        int r = r0 + rr;
        if (r >= M) return;               // rows ascend; safe early-out
        int b = r / SEQ, s = r - b * SEQ;
        const float* xr = &x[(size_t)b * LIN + s * 4];
        float4 xa = *reinterpret_cast<const float4*>(xr);
        float4 xc = *reinterpret_cast<const float4*>(xr + 4);
        float xi[8] = {xa.x, xa.y, xa.z, xa.w, xc.x, xc.y, xc.z, xc.w};
        float4 pv = *reinterpret_cast<const float4*>(&pe[s * EMB + e0]);
        const float* bpa = reinterpret_cast<const float*>(&bpv);
        const float* pva = reinterpret_cast<const float*>(&pv);
        float y[4];
#pragma unroll
        for (int c = 0; c < 4; ++c) {
            float acc = bpa[c];
#pragma unroll
            for (int j = 0; j < 8; ++j) acc += xi[j] * wreg[j][c];
            y[c] = fmaxf(acc, 0.f) + pva[c];
        }
        uint2 o;
        o.x = cvt_pk_bf16(y[0], y[1]);
        o.y = cvt_pk_bf16(y[2], y[3]);
        *reinterpret_cast<uint2*>(&Xb[(size_t)r * EMB + e0]) = o;
    }
}

// ---------------- MFMA bf16 GEMM: C[m,n] = sum_k A[m,k] * W[n,k], C in bf16
// grid = (6, Mtiles): A-sharing blocks dispatch-adjacent -> A from L2/L3.
__global__ __launch_bounds__(256) void gemm_qkv_mfma(
    const __hip_bfloat16* __restrict__ A,    // [Mpad][256]
    const __hip_bfloat16* __restrict__ Wset, // [3][256][256]
    __hip_bfloat16* __restrict__ Q, __hip_bfloat16* __restrict__ K,
    __hip_bfloat16* __restrict__ V, int M)
{
    int by = blockIdx.x;                       // 0..5
    int wsel = by >> 1;
    const __hip_bfloat16* W = Wset + (size_t)wsel * EMB * EMB;
    __hip_bfloat16* C = (wsel == 0) ? Q : (wsel == 1 ? K : V);
    int nbase = (by & 1) * 128;
    int mbase = blockIdx.y * 128;

    __shared__ __hip_bfloat16 As[128][64];
    __shared__ __hip_bfloat16 Bs[128][64];

    int tid  = threadIdx.x;
    int wave = tid >> 6, lane = tid & 63;
    int wr = wave >> 1, wc = wave & 1;

    int r0   = tid >> 3;
    int srcs = (tid & 7) ^ (r0 & 7);
    const __hip_bfloat16* gA = A + (size_t)(mbase + r0) * EMB + srcs * 8;
    const __hip_bfloat16* gB = W + (size_t)(nbase + r0) * EMB + srcs * 8;

    f32x4 acc[4][4];
#pragma unroll
    for (int i = 0; i < 4; ++i)
#pragma unroll
        for (int j = 0; j < 4; ++j) acc[i][j] = (f32x4){0.f, 0.f, 0.f, 0.f};

    for (int kt = 0; kt < EMB; kt += 64) {
        if (kt) __syncthreads();
#pragma unroll
        for (int i = 0; i < 4; ++i) {
            __hip_bfloat16* l = &As[0][0] + i * 2048 + tid * 8;
            __builtin_amdgcn_global_load_lds(
                (const __attribute__((address_space(1))) void*)(gA + (size_t)i * 32 * EMB + kt),
                (__attribute__((address_space(3))) void*)l, 16, 0, 0);
        }
#pragma unroll
        for (int i = 0; i < 4; ++i) {
            __hip_bfloat16* l = &Bs[0][0] + i * 2048 + tid * 8;
            __builtin_amdgcn_global_load_lds(
                (const __attribute__((address_space(1))) void*)(gB + (size_t)i * 32 * EMB + kt),
                (__attribute__((address_space(3))) void*)l, 16, 0, 0);
        }
        asm volatile("s_waitcnt vmcnt(0)" ::: "memory");
        __syncthreads();

#pragma unroll
        for (int kk = 0; kk < 2; ++kk) {
            bf16x8 af[4], bfr[4];
            int sg = kk * 4 + (lane >> 4);
#pragma unroll
            for (int mi = 0; mi < 4; ++mi) {
                int row = wr * 64 + mi * 16 + (lane & 15);
                int sl  = sg ^ (row & 7);
                af[mi] = *reinterpret_cast<const bf16x8*>(&As[row][sl * 8]);
            }
#pragma unroll
            for (int ni = 0; ni < 4; ++ni) {
                int row = wc * 64 + ni * 16 + (lane & 15);
                int sl  = sg ^ (row & 7);
                bfr[ni] = *reinterpret_cast<const bf16x8*>(&Bs[row][sl * 8]);
            }
#pragma unroll
            for (int mi = 0; mi < 4; ++mi)
#pragma unroll
                for (int ni = 0; ni < 4; ++ni)
                    acc[mi][ni] = __builtin_amdgcn_mfma_f32_16x16x32_bf16(
                        af[mi], bfr[ni], acc[mi][ni], 0, 0, 0);
        }
    }

    int rg = lane >> 4, cli = lane & 15;
#pragma unroll
    for (int mi = 0; mi < 4; ++mi)
#pragma unroll
        for (int j = 0; j < 4; ++j) {
            int m = mbase + wr * 64 + mi * 16 + rg * 4 + j;
            if (m < M) {
#pragma unroll
                for (int ni = 0; ni < 4; ++ni)
                    C[(size_t)m * EMB + nbase + wc * 64 + ni * 16 + cli] =
                        __float2bfloat16(acc[mi][ni][j]);
            }
        }
}

// ---------------- MFMA flash attention v5 (byte-exact round-13 body).
// NOTE: rounds 14/15 both NaN'd with a value-identical "factored softmax
// weight" refactor (sfc/tbc hoisting) — root cause not localized; do NOT
// reapply that variant without an on-HW disassembly A/B.
__global__ __launch_bounds__(256) void attn_mfma_kernel(
    const __hip_bfloat16* __restrict__ Qb, const __hip_bfloat16* __restrict__ Kb,
    const __hip_bfloat16* __restrict__ Vb, __hip_bfloat16* __restrict__ O)
{
    int bh = blockIdx.x;
    int b = bh >> 3, h = bh & 7;
    const size_t base = (size_t)b * SEQ * EMB + (size_t)h * HD;

    __shared__ short K2[96][64];          // 12288 B, XOR-swizzled
    __shared__ short Vt[32][212];         // 13568 B, stride 212 -> <=2-way

    int tid  = threadIdx.x;
    int wave = tid >> 6, lane = tid & 63;
    int cl = lane & 15, rg = lane >> 4;

    // ---- stage K (swizzled b128 writes)
    for (int u = tid; u < 192 * 4; u += 256) {
        int t = u >> 2, d0 = (u & 3) << 3;
        uint4 kv = make_uint4(0, 0, 0, 0);
        if (t < SEQ) kv = *reinterpret_cast<const uint4*>(&Kb[base + (size_t)t * EMB + d0]);
        int krow = t >> 1;
        int kphy = (((t & 1) * 4 + (d0 >> 3)) ^ (krow & 7));
        *reinterpret_cast<uint4*>(&K2[krow][kphy * 8]) = kv;
    }
    // ---- stage V^T: register quad-transpose, b64 writes
    if (tid < 192) {
        int tq = tid >> 2, d0 = (tid & 3) << 3;
        int t0 = tq * 4;
        uint4 r0 = make_uint4(0,0,0,0), r1 = r0, r2 = r0, r3 = r0;
        if (t0 + 0 < SEQ) r0 = *reinterpret_cast<const uint4*>(&Vb[base + (size_t)(t0+0)*EMB + d0]);
        if (t0 + 1 < SEQ) r1 = *reinterpret_cast<const uint4*>(&Vb[base + (size_t)(t0+1)*EMB + d0]);
        if (t0 + 2 < SEQ) r2 = *reinterpret_cast<const uint4*>(&Vb[base + (size_t)(t0+2)*EMB + d0]);
        if (t0 + 3 < SEQ) r3 = *reinterpret_cast<const uint4*>(&Vb[base + (size_t)(t0+3)*EMB + d0]);
        const unsigned* q0 = reinterpret_cast<const unsigned*>(&r0);
        const unsigned* q1 = reinterpret_cast<const unsigned*>(&r1);
        const unsigned* q2 = reinterpret_cast<const unsigned*>(&r2);
        const unsigned* q3 = reinterpret_cast<const unsigned*>(&r3);
#pragma unroll
        for (int k = 0; k < 8; ++k) {
            int dw = k >> 1, sh = (k & 1) * 16;
            unsigned a0 = (q0[dw] >> sh) & 0xffffu;
            unsigned a1 = (q1[dw] >> sh) & 0xffffu;
            unsigned a2 = (q2[dw] >> sh) & 0xffffu;
            unsigned a3 = (q3[dw] >> sh) & 0xffffu;
            uint2 w;
            w.x = a0 | (a1 << 16);
            w.y = a2 | (a3 << 16);
            *reinterpret_cast<uint2*>(&Vt[d0 + k][t0]) = w;
        }
    }
    __syncthreads();

    const float csw2 = (0.0625f / (float)SEQ) * 1.4426950408889634f;

    for (int qt = 0; qt < 3; ++qt) {
        int qbase = wave * 48 + qt * 16;
        int sq = qbase + cl;
        bf16x8 aq = {};
        if (sq < SEQ)
            aq = *reinterpret_cast<const bf16x8*>(&Qb[base + (size_t)sq * EMB + rg * 8]);
        float sf = (float)sq;

        f32x4 olo = {0.f, 0.f, 0.f, 0.f}, ohi = {0.f, 0.f, 0.f, 0.f};
        float lrow = 0.f;

#pragma unroll
        for (int blk = 0; blk < 6; ++blk) {
            // ---- K^T Q for two 16-t tiles (C: lane q=cl, t=rg*4+j)
            f32x4 s1, s2;
            {
                int t = blk * 32 + cl;
                int kr = t >> 1;
                int kph = (((t & 1) * 4 + rg) ^ (kr & 7));
                bf16x8 kf = *reinterpret_cast<const bf16x8*>(&K2[kr][kph * 8]);
                s1 = __builtin_amdgcn_mfma_f32_16x16x32_bf16(
                    kf, aq, (f32x4){0.f, 0.f, 0.f, 0.f}, 0, 0, 0);
            }
            {
                int t = blk * 32 + 16 + cl;
                int kr = t >> 1;
                int kph = (((t & 1) * 4 + rg) ^ (kr & 7));
                bf16x8 kf = *reinterpret_cast<const bf16x8*>(&K2[kr][kph * 8]);
                s2 = __builtin_amdgcn_mfma_f32_16x16x32_bf16(
                    kf, aq, (f32x4){0.f, 0.f, 0.f, 0.f}, 0, 0, 0);
            }

            // ---- weight + exp (no-max softmax: |logit| <= ~0.2)
            int tb1 = blk * 32 + rg * 4;
            int tb2 = tb1 + 16;
            float p1[4], p2[4];
#pragma unroll
            for (int j = 0; j < 4; ++j) {
                p1[j] = exp2f(s1[j] * (fabsf(sf - (float)(tb1 + j)) * csw2));
                p2[j] = exp2f(s2[j] * (fabsf(sf - (float)(tb2 + j)) * csw2));
            }
            if (blk == 5) {                       // only tile2 holds t >= SEQ
#pragma unroll
                for (int j = 0; j < 4; ++j)
                    if (tb2 + j >= SEQ) p2[j] = 0.f;
            }
            lrow += ((p1[0] + p1[1]) + (p1[2] + p1[3]))
                  + ((p2[0] + p2[1]) + (p2[2] + p2[3]));

            // ---- P fragments: cvt_pk pairs ARE the 16x16x16 B-operand
            uint2 u1, u2;
            u1.x = cvt_pk_bf16(p1[0], p1[1]);
            u1.y = cvt_pk_bf16(p1[2], p1[3]);
            u2.x = cvt_pk_bf16(p2[0], p2[1]);
            u2.y = cvt_pk_bf16(p2[2], p2[3]);
            bf16x4 pf1 = *reinterpret_cast<bf16x4*>(&u1);
            bf16x4 pf2 = *reinterpret_cast<bf16x4*>(&u2);

            // ---- PV: O^T[d][q] += V^T[d][t] * P^T[t][q], two 16-t tiles
            int tA = blk * 32 + rg * 4;
            bf16x4 v1lo = *reinterpret_cast<const bf16x4*>(&Vt[cl][tA]);
            bf16x4 v2lo = *reinterpret_cast<const bf16x4*>(&Vt[cl][tA + 16]);
            bf16x4 v1hi = *reinterpret_cast<const bf16x4*>(&Vt[cl + 16][tA]);
            bf16x4 v2hi = *reinterpret_cast<const bf16x4*>(&Vt[cl + 16][tA + 16]);
            olo = mfma16x16x16(v1lo, pf1, olo);
            olo = mfma16x16x16(v2lo, pf2, olo);
            ohi = mfma16x16x16(v1hi, pf1, ohi);
            ohi = mfma16x16x16(v2hi, pf2, ohi);
        }

        // ---- row sum: q=cl lane-local; reduce over the 4 rg groups
        lrow += __shfl_xor(lrow, 16);
        lrow += __shfl_xor(lrow, 32);

        // ---- store: lane owns O[q=sq][d = rg*4..+3 and +16], b64 each
        if (sq < SEQ) {
            float rl = 1.0f / lrow;
            __hip_bfloat16* op = &O[base + (size_t)sq * EMB];
            uint2 wlo, whi;
            wlo.x = cvt_pk_bf16(olo[0] * rl, olo[1] * rl);
            wlo.y = cvt_pk_bf16(olo[2] * rl, olo[3] * rl);
            whi.x = cvt_pk_bf16(ohi[0] * rl, ohi[1] * rl);
            whi.y = cvt_pk_bf16(ohi[2] * rl, ohi[3] * rl);
            *reinterpret_cast<uint2*>(&op[rg * 4])      = wlo;
            *reinterpret_cast<uint2*>(&op[16 + rg * 4]) = whi;
        }
    }
}

// ---------------- row LayerNorm + PE: wave-per-row, 4 rows/block, bf16 io
__global__ __launch_bounds__(256) void ln_pe4_kernel(
    const __hip_bfloat16* __restrict__ X, const float* __restrict__ g,
    const float* __restrict__ bb, const float* __restrict__ pe,
    __hip_bfloat16* __restrict__ Xb, int M)
{
    int r = blockIdx.x * 4 + (threadIdx.x >> 6);
    if (r >= M) return;
    int lane = threadIdx.x & 63;
    int s = r % SEQ;
    int c0 = lane * 4;

    uint2 raw = *reinterpret_cast<const uint2*>(&X[(size_t)r * EMB + c0]);
    float v[4];
    v[0] = __uint_as_float((raw.x & 0xffffu) << 16);
    v[1] = __uint_as_float(raw.x & 0xffff0000u);
    v[2] = __uint_as_float((raw.y & 0xffffu) << 16);
    v[3] = __uint_as_float(raw.y & 0xffff0000u);

    float sum = v[0] + v[1] + v[2] + v[3];
    float sq  = v[0]*v[0] + v[1]*v[1] + v[2]*v[2] + v[3]*v[3];
#pragma unroll
    for (int off = 32; off > 0; off >>= 1) {
        sum += __shfl_xor(sum, off);
        sq  += __shfl_xor(sq,  off);
    }
    float mu  = sum * (1.0f / EMB);
    float var = sq * (1.0f / EMB) - mu * mu;
    float is  = rsqrtf(var + EPSV);

    float4 gv = *reinterpret_cast<const float4*>(&g[c0]);
    float4 bv = *reinterpret_cast<const float4*>(&bb[c0]);
    float4 pv = *reinterpret_cast<const float4*>(&pe[s * EMB + c0]);
    float y0 = (v[0] - mu) * is * gv.x + bv.x + pv.x;
    float y1 = (v[1] - mu) * is * gv.y + bv.y + pv.y;
    float y2 = (v[2] - mu) * is * gv.z + bv.z + pv.z;
    float y3 = (v[3] - mu) * is * gv.w + bv.w + pv.w;

    uint2 o;
    o.x = cvt_pk_bf16(y0, y1);
    o.y = cvt_pk_bf16(y2, y3);
    *reinterpret_cast<uint2*>(&Xb[(size_t)r * EMB + c0]) = o;
}

// ------- fused: LN(lnA2) -> LN(ln2) -> mean-pool over SEQ -> FC[10], 16 waves
__global__ __launch_bounds__(1024) void lnfc_kernel(
    const __hip_bfloat16* __restrict__ X,
    const float* __restrict__ g1, const float* __restrict__ b1,
    const float* __restrict__ g2, const float* __restrict__ b2,
    const float* __restrict__ ow, const float* __restrict__ ob,
    float* __restrict__ out)
{
    int b    = blockIdx.x;
    int tid  = threadIdx.x;
    int wave = tid >> 6, lane = tid & 63;

    float g1v[4], b1v[4], g2v[4], b2v[4], pooled[4];
#pragma unroll
    for (int j = 0; j < 4; ++j) {
        int c = lane + 64 * j;
        g1v[j] = g1[c]; b1v[j] = b1[c];
        g2v[j] = g2[c]; b2v[j] = b2[c];
        pooled[j] = 0.f;
    }

    for (int s = wave; s < SEQ; s += 16) {
        const __hip_bfloat16* row = &X[((size_t)b * SEQ + s) * EMB];
        float v[4];
#pragma unroll
        for (int j = 0; j < 4; ++j) v[j] = __bfloat162float(row[lane + 64 * j]);

        float sum = v[0] + v[1] + v[2] + v[3];
        float sq  = v[0]*v[0] + v[1]*v[1] + v[2]*v[2] + v[3]*v[3];
#pragma unroll
        for (int off = 32; off > 0; off >>= 1) {
            sum += __shfl_xor(sum, off);
            sq  += __shfl_xor(sq,  off);
        }
        float mu  = sum * (1.0f / EMB);
        float var = sq * (1.0f / EMB) - mu * mu;
        float is  = rsqrtf(var + EPSV);
        float y[4];
#pragma unroll
        for (int j = 0; j < 4; ++j) y[j] = (v[j] - mu) * is * g1v[j] + b1v[j];

        sum = y[0] + y[1] + y[2] + y[3];
        sq  = y[0]*y[0] + y[1]*y[1] + y[2]*y[2] + y[3]*y[3];
#pragma unroll
        for (int off = 32; off > 0; off >>= 1) {
            sum += __shfl_xor(sum, off);
            sq  += __shfl_xor(sq,  off);
        }
        mu  = sum * (1.0f / EMB);
        var = sq * (1.0f / EMB) - mu * mu;
        is  = rsqrtf(var + EPSV);
#pragma unroll
        for (int j = 0; j < 4; ++j) pooled[j] += (y[j] - mu) * is * g2v[j] + b2v[j];
    }

    __shared__ float pp[16][EMB];
#pragma unroll
    for (int j = 0; j < 4; ++j) pp[wave][lane + 64 * j] = pooled[j];
    __syncthreads();
    __shared__ float pool[EMB];
    if (tid < EMB) {
        float pl = 0.f;
#pragma unroll
        for (int w = 0; w < 16; ++w) pl += pp[w][tid];
        pool[tid] = pl * (1.0f / (float)SEQ);
    }
    __syncthreads();
    if (tid < 10) {
        float o = ob[tid];
        for (int k = 0; k < EMB; ++k) o += pool[k] * ow[tid * EMB + k];
        out[b * 10 + tid] = o;
    }
}

// ---------------------------------------------------------------- launch
extern "C" void kernel_launch(void* const* d_in, const int* in_sizes, int n_in,
                              void* d_out, int out_size, void* d_ws, size_t ws_size,
                              hipStream_t stream)
{
    const float* x      = (const float*)d_in[0];
    const float* conv_w = (const float*)d_in[1];
    const float* conv_b = (const float*)d_in[2];
    const float* bn_g   = (const float*)d_in[3];
    const float* bn_b   = (const float*)d_in[4];
    const float* bn_m   = (const float*)d_in[5];
    const float* bn_v   = (const float*)d_in[6];
    const float* wq1    = (const float*)d_in[7];
    const float* wk1    = (const float*)d_in[8];
    const float* wv1    = (const float*)d_in[9];
    const float* lnA1_g = (const float*)d_in[10];
    const float* lnA1_b = (const float*)d_in[11];
    const float* wq2    = (const float*)d_in[12];
    const float* wk2    = (const float*)d_in[13];
    const float* wv2    = (const float*)d_in[14];
    const float* lnA2_g = (const float*)d_in[15];
    const float* lnA2_b = (const float*)d_in[16];
    const float* ln2_g  = (const float*)d_in[17];
    const float* ln2_b  = (const float*)d_in[18];
    const float* out_w  = (const float*)d_in[19];
    const float* out_b  = (const float*)d_in[20];
    float* out = (float*)d_out;

    const size_t peN = (size_t)SEQ * EMB;
    const size_t wN  = (size_t)EMB * EMB;
    const size_t foldN = 8 * EMB + EMB;           // wt[8][256] + bp[256]

    int chunk = B_TOT;
    while (chunk > 1) {
        size_t M    = (size_t)chunk * SEQ;
        size_t Mpad = (M + 127) / 128 * 128;
        size_t need = (peN + foldN) * 4 + 6 * wN * 2 + (Mpad + 4 * M) * EMB * 2;
        if (need <= ws_size) break;
        chunk >>= 1;
    }
    size_t M    = (size_t)chunk * SEQ;
    size_t Mpad = (M + 127) / 128 * 128;

    float*          pe = (float*)d_ws;
    float*          wt = pe + peN;
    float*          bp = wt + 8 * EMB;
    __hip_bfloat16* Wb = (__hip_bfloat16*)(bp + EMB);
    __hip_bfloat16* Xb = Wb + 6 * wN;
    __hip_bfloat16* Ob = Xb + Mpad * EMB;
    __hip_bfloat16* Qb = Ob + M * EMB;
    __hip_bfloat16* Kb = Qb + M * EMB;
    __hip_bfloat16* Vb = Kb + M * EMB;

    pe_kernel<<<(SEQ * EMB + 255) / 256, 256, 0, stream>>>(pe);
    fold_conv_kernel<<<1, 256, 0, stream>>>(conv_w, conv_b, bn_g, bn_b, bn_m, bn_v, wt, bp);
    {
        dim3 cg((unsigned)(wN / 1024), 6);
        cvt6_kernel<<<cg, 256, 0, stream>>>(wq1, wk1, wv1, wq2, wk2, wv2, Wb, (int)wN);
    }

    for (int b0 = 0; b0 < B_TOT; b0 += chunk) {
        int Bc = chunk;
        int Mi = Bc * SEQ;
        dim3 ggrid(6, (unsigned)(Mpad / 128));

        embed_kernel<<<(Mi + 15) / 16, 256, 0, stream>>>(
            x + (size_t)b0 * LIN, wt, bp, pe, Xb, Mi);

        // --- attention block 1 ---
        gemm_qkv_mfma<<<ggrid, 256, 0, stream>>>(Xb, Wb, Qb, Kb, Vb, Mi);
        attn_mfma_kernel<<<Bc * HEADS, 256, 0, stream>>>(Qb, Kb, Vb, Ob);
        ln_pe4_kernel<<<(Mi + 3) / 4, 256, 0, stream>>>(Ob, lnA1_g, lnA1_b, pe, Xb, Mi);

        // --- attention block 2 ---
        gemm_qkv_mfma<<<ggrid, 256, 0, stream>>>(Xb, Wb + 3 * wN, Qb, Kb, Vb, Mi);
        attn_mfma_kernel<<<Bc * HEADS, 256, 0, stream>>>(Qb, Kb, Vb, Ob);
        lnfc_kernel<<<Bc, 1024, 0, stream>>>(Ob, lnA2_g, lnA2_b, ln2_g, ln2_b,
                                             out_w, out_b, out + (size_t)b0 * 10);
    }
}

// Round 17
// 331.791 us; speedup vs baseline: 1.3411x; 1.0306x over previous
//
#include <hip/hip_runtime.h>
#include <hip/hip_bf16.h>
#include <math.h>

#define B_TOT 512
#define SEQ   179
#define EMB   256
#define HEADS 8
#define HD    32
#define LIN   720
#define EPSV  1e-5f

typedef __attribute__((ext_vector_type(8))) short bf16x8;
typedef __attribute__((ext_vector_type(4))) short bf16x4;
typedef __attribute__((ext_vector_type(4))) float f32x4;

__device__ __forceinline__ unsigned cvt_pk_bf16(float lo, float hi) {
    unsigned r;
    asm("v_cvt_pk_bf16_f32 %0, %1, %2" : "=v"(r) : "v"(lo), "v"(hi));
    return r;
}

__device__ __forceinline__ f32x4 mfma16x16x16(bf16x4 a, bf16x4 b, f32x4 c) {
#if __has_builtin(__builtin_amdgcn_mfma_f32_16x16x16bf16_1k)
    return __builtin_amdgcn_mfma_f32_16x16x16bf16_1k(a, b, c, 0, 0, 0);
#else
    asm volatile("v_mfma_f32_16x16x16_bf16 %0, %1, %2, %0"
                 : "+v"(c) : "v"(a), "v"(b));
    return c;
#endif
}

// ---------------------------------------------------------------- PE table
__global__ void pe_kernel(float* __restrict__ pe) {
    int idx = blockIdx.x * 256 + threadIdx.x;
    if (idx >= SEQ * EMB) return;
    int s = idx / EMB, e = idx % EMB;
    int i = e >> 1;
    float dv  = expf((float)(2 * i) * (-9.210340371976184f / (float)EMB));
    float ang = (float)s * dv * ((float)EMB / (float)SEQ);
    pe[idx] = (e & 1) ? cosf(ang) : sinf(ang);
}

// --------------- one-time: fold BN into conv weights; wt transposed [8][256]
__global__ void fold_conv_kernel(const float* __restrict__ cw, const float* __restrict__ cb,
                                 const float* __restrict__ g, const float* __restrict__ bb,
                                 const float* __restrict__ mean, const float* __restrict__ var,
                                 float* __restrict__ wt, float* __restrict__ bp) {
    int e = threadIdx.x;                  // 256 threads, 1 block
    float is = g[e] * rsqrtf(var[e] + EPSV);
#pragma unroll
    for (int j = 0; j < 8; ++j) wt[j * EMB + e] = cw[e * 8 + j] * is;
    bp[e] = (cb[e] - mean[e]) * is + bb[e];
}

// ------------------------------------- f32 -> bf16 convert, 6 weights at once
__global__ void cvt6_kernel(const float* __restrict__ s0, const float* __restrict__ s1,
                            const float* __restrict__ s2, const float* __restrict__ s3,
                            const float* __restrict__ s4, const float* __restrict__ s5,
                            __hip_bfloat16* __restrict__ dst, int n) {
    int w = blockIdx.y;
    const float* src = (w == 0) ? s0 : (w == 1) ? s1 : (w == 2) ? s2
                     : (w == 3) ? s3 : (w == 4) ? s4 : s5;
    __hip_bfloat16* d = dst + (size_t)w * n;
    int i = (blockIdx.x * 256 + threadIdx.x) * 4;
    if (i < n) {
        float4 v = *reinterpret_cast<const float4*>(&src[i]);
        d[i + 0] = __float2bfloat16(v.x);
        d[i + 1] = __float2bfloat16(v.y);
        d[i + 2] = __float2bfloat16(v.z);
        d[i + 3] = __float2bfloat16(v.w);
    }
}

// ------------ embed v3: conv(stride4,K8,BN-folded) + ReLU + PE -> bf16
__global__ __launch_bounds__(256) void embed_kernel(
    const float* __restrict__ x, const float* __restrict__ wt,
    const float* __restrict__ bp, const float* __restrict__ pe,
    __hip_bfloat16* __restrict__ Xb, int M)
{
    int lane = threadIdx.x & 63;
    int wv   = threadIdx.x >> 6;
    int e0   = lane * 4;

    float wreg[8][4];
#pragma unroll
    for (int j = 0; j < 8; ++j)
        *reinterpret_cast<float4*>(wreg[j]) = *reinterpret_cast<const float4*>(&wt[j * EMB + e0]);
    float4 bpv = *reinterpret_cast<const float4*>(&bp[e0]);

    int r0 = blockIdx.x * 16 + wv * 4;
#pragma unroll
    for (int rr = 0; rr < 4; ++rr) {
        int r = r0 + rr;
        if (r >= M) return;               // rows ascend; safe early-out
        int b = r / SEQ, s = r - b * SEQ;
        const float* xr = &x[(size_t)b * LIN + s * 4];
        float4 xa = *reinterpret_cast<const float4*>(xr);
        float4 xc = *reinterpret_cast<const float4*>(xr + 4);
        float xi[8] = {xa.x, xa.y, xa.z, xa.w, xc.x, xc.y, xc.z, xc.w};
        float4 pv = *reinterpret_cast<const float4*>(&pe[s * EMB + e0]);
        const float* bpa = reinterpret_cast<const float*>(&bpv);
        const float* pva = reinterpret_cast<const float*>(&pv);
        float y[4];
#pragma unroll
        for (int c = 0; c < 4; ++c) {
            float acc = bpa[c];
#pragma unroll
            for (int j = 0; j < 8; ++j) acc += xi[j] * wreg[j][c];
            y[c] = fmaxf(acc, 0.f) + pva[c];
        }
        uint2 o;
        o.x = cvt_pk_bf16(y[0], y[1]);
        o.y = cvt_pk_bf16(y[2], y[3]);
        *reinterpret_cast<uint2*>(&Xb[(size_t)r * EMB + e0]) = o;
    }
}

// ---------------- MFMA bf16 GEMM: C[m,n] = sum_k A[m,k] * W[n,k], C in bf16
// 1-D grid with bijective XCD swizzle (m204): each XCD owns a contiguous
// work range, so the 6 N-blocks sharing an A-strip run on ONE XCD's L2.
__global__ __launch_bounds__(256) void gemm_qkv_mfma(
    const __hip_bfloat16* __restrict__ A,    // [Mpad][256]
    const __hip_bfloat16* __restrict__ Wset, // [3][256][256]
    __hip_bfloat16* __restrict__ Q, __hip_bfloat16* __restrict__ K,
    __hip_bfloat16* __restrict__ V, int M)
{
    // ---- XCD swizzle: dispatch id -> work id (bijective, any nwg)
    unsigned id  = blockIdx.x;
    unsigned nwg = gridDim.x;
    unsigned qq  = nwg >> 3, rr_ = nwg & 7;
    unsigned xcd = id & 7, slot = id >> 3;
    unsigned work = xcd * qq + (xcd < rr_ ? xcd : rr_) + slot;

    int by = (int)(work % 6);                  // 0..5 : weight + N-half
    int wsel = by >> 1;
    const __hip_bfloat16* W = Wset + (size_t)wsel * EMB * EMB;
    __hip_bfloat16* C = (wsel == 0) ? Q : (wsel == 1 ? K : V);
    int nbase = (by & 1) * 128;
    int mbase = (int)(work / 6) * 128;

    __shared__ __hip_bfloat16 As[128][64];
    __shared__ __hip_bfloat16 Bs[128][64];

    int tid  = threadIdx.x;
    int wave = tid >> 6, lane = tid & 63;
    int wr = wave >> 1, wc = wave & 1;

    int r0   = tid >> 3;
    int srcs = (tid & 7) ^ (r0 & 7);
    const __hip_bfloat16* gA = A + (size_t)(mbase + r0) * EMB + srcs * 8;
    const __hip_bfloat16* gB = W + (size_t)(nbase + r0) * EMB + srcs * 8;

    f32x4 acc[4][4];
#pragma unroll
    for (int i = 0; i < 4; ++i)
#pragma unroll
        for (int j = 0; j < 4; ++j) acc[i][j] = (f32x4){0.f, 0.f, 0.f, 0.f};

    for (int kt = 0; kt < EMB; kt += 64) {
        if (kt) __syncthreads();
#pragma unroll
        for (int i = 0; i < 4; ++i) {
            __hip_bfloat16* l = &As[0][0] + i * 2048 + tid * 8;
            __builtin_amdgcn_global_load_lds(
                (const __attribute__((address_space(1))) void*)(gA + (size_t)i * 32 * EMB + kt),
                (__attribute__((address_space(3))) void*)l, 16, 0, 0);
        }
#pragma unroll
        for (int i = 0; i < 4; ++i) {
            __hip_bfloat16* l = &Bs[0][0] + i * 2048 + tid * 8;
            __builtin_amdgcn_global_load_lds(
                (const __attribute__((address_space(1))) void*)(gB + (size_t)i * 32 * EMB + kt),
                (__attribute__((address_space(3))) void*)l, 16, 0, 0);
        }
        asm volatile("s_waitcnt vmcnt(0)" ::: "memory");
        __syncthreads();

#pragma unroll
        for (int kk = 0; kk < 2; ++kk) {
            bf16x8 af[4], bfr[4];
            int sg = kk * 4 + (lane >> 4);
#pragma unroll
            for (int mi = 0; mi < 4; ++mi) {
                int row = wr * 64 + mi * 16 + (lane & 15);
                int sl  = sg ^ (row & 7);
                af[mi] = *reinterpret_cast<const bf16x8*>(&As[row][sl * 8]);
            }
#pragma unroll
            for (int ni = 0; ni < 4; ++ni) {
                int row = wc * 64 + ni * 16 + (lane & 15);
                int sl  = sg ^ (row & 7);
                bfr[ni] = *reinterpret_cast<const bf16x8*>(&Bs[row][sl * 8]);
            }
#pragma unroll
            for (int mi = 0; mi < 4; ++mi)
#pragma unroll
                for (int ni = 0; ni < 4; ++ni)
                    acc[mi][ni] = __builtin_amdgcn_mfma_f32_16x16x32_bf16(
                        af[mi], bfr[ni], acc[mi][ni], 0, 0, 0);
        }
    }

    int rg = lane >> 4, cli = lane & 15;
#pragma unroll
    for (int mi = 0; mi < 4; ++mi)
#pragma unroll
        for (int j = 0; j < 4; ++j) {
            int m = mbase + wr * 64 + mi * 16 + rg * 4 + j;
            if (m < M) {
#pragma unroll
                for (int ni = 0; ni < 4; ++ni)
                    C[(size_t)m * EMB + nbase + wc * 64 + ni * 16 + cli] =
                        __float2bfloat16(acc[mi][ni][j]);
            }
        }
}

// ---------------- MFMA flash attention v5 (byte-exact round-13 body).
// NOTE: rounds 14/15 both NaN'd with a value-identical "factored softmax
// weight" refactor (sfc/tbc hoisting) — root cause not localized; do NOT
// reapply that variant without an on-HW disassembly A/B.
__global__ __launch_bounds__(256) void attn_mfma_kernel(
    const __hip_bfloat16* __restrict__ Qb, const __hip_bfloat16* __restrict__ Kb,
    const __hip_bfloat16* __restrict__ Vb, __hip_bfloat16* __restrict__ O)
{
    int bh = blockIdx.x;
    int b = bh >> 3, h = bh & 7;
    const size_t base = (size_t)b * SEQ * EMB + (size_t)h * HD;

    __shared__ short K2[96][64];          // 12288 B, XOR-swizzled
    __shared__ short Vt[32][212];         // 13568 B, stride 212 -> <=2-way

    int tid  = threadIdx.x;
    int wave = tid >> 6, lane = tid & 63;
    int cl = lane & 15, rg = lane >> 4;

    // ---- stage K (swizzled b128 writes)
    for (int u = tid; u < 192 * 4; u += 256) {
        int t = u >> 2, d0 = (u & 3) << 3;
        uint4 kv = make_uint4(0, 0, 0, 0);
        if (t < SEQ) kv = *reinterpret_cast<const uint4*>(&Kb[base + (size_t)t * EMB + d0]);
        int krow = t >> 1;
        int kphy = (((t & 1) * 4 + (d0 >> 3)) ^ (krow & 7));
        *reinterpret_cast<uint4*>(&K2[krow][kphy * 8]) = kv;
    }
    // ---- stage V^T: register quad-transpose, b64 writes
    if (tid < 192) {
        int tq = tid >> 2, d0 = (tid & 3) << 3;
        int t0 = tq * 4;
        uint4 r0 = make_uint4(0,0,0,0), r1 = r0, r2 = r0, r3 = r0;
        if (t0 + 0 < SEQ) r0 = *reinterpret_cast<const uint4*>(&Vb[base + (size_t)(t0+0)*EMB + d0]);
        if (t0 + 1 < SEQ) r1 = *reinterpret_cast<const uint4*>(&Vb[base + (size_t)(t0+1)*EMB + d0]);
        if (t0 + 2 < SEQ) r2 = *reinterpret_cast<const uint4*>(&Vb[base + (size_t)(t0+2)*EMB + d0]);
        if (t0 + 3 < SEQ) r3 = *reinterpret_cast<const uint4*>(&Vb[base + (size_t)(t0+3)*EMB + d0]);
        const unsigned* q0 = reinterpret_cast<const unsigned*>(&r0);
        const unsigned* q1 = reinterpret_cast<const unsigned*>(&r1);
        const unsigned* q2 = reinterpret_cast<const unsigned*>(&r2);
        const unsigned* q3 = reinterpret_cast<const unsigned*>(&r3);
#pragma unroll
        for (int k = 0; k < 8; ++k) {
            int dw = k >> 1, sh = (k & 1) * 16;
            unsigned a0 = (q0[dw] >> sh) & 0xffffu;
            unsigned a1 = (q1[dw] >> sh) & 0xffffu;
            unsigned a2 = (q2[dw] >> sh) & 0xffffu;
            unsigned a3 = (q3[dw] >> sh) & 0xffffu;
            uint2 w;
            w.x = a0 | (a1 << 16);
            w.y = a2 | (a3 << 16);
            *reinterpret_cast<uint2*>(&Vt[d0 + k][t0]) = w;
        }
    }
    __syncthreads();

    const float csw2 = (0.0625f / (float)SEQ) * 1.4426950408889634f;

    for (int qt = 0; qt < 3; ++qt) {
        int qbase = wave * 48 + qt * 16;
        int sq = qbase + cl;
        bf16x8 aq = {};
        if (sq < SEQ)
            aq = *reinterpret_cast<const bf16x8*>(&Qb[base + (size_t)sq * EMB + rg * 8]);
        float sf = (float)sq;

        f32x4 olo = {0.f, 0.f, 0.f, 0.f}, ohi = {0.f, 0.f, 0.f, 0.f};
        float lrow = 0.f;

#pragma unroll
        for (int blk = 0; blk < 6; ++blk) {
            // ---- K^T Q for two 16-t tiles (C: lane q=cl, t=rg*4+j)
            f32x4 s1, s2;
            {
                int t = blk * 32 + cl;
                int kr = t >> 1;
                int kph = (((t & 1) * 4 + rg) ^ (kr & 7));
                bf16x8 kf = *reinterpret_cast<const bf16x8*>(&K2[kr][kph * 8]);
                s1 = __builtin_amdgcn_mfma_f32_16x16x32_bf16(
                    kf, aq, (f32x4){0.f, 0.f, 0.f, 0.f}, 0, 0, 0);
            }
            {
                int t = blk * 32 + 16 + cl;
                int kr = t >> 1;
                int kph = (((t & 1) * 4 + rg) ^ (kr & 7));
                bf16x8 kf = *reinterpret_cast<const bf16x8*>(&K2[kr][kph * 8]);
                s2 = __builtin_amdgcn_mfma_f32_16x16x32_bf16(
                    kf, aq, (f32x4){0.f, 0.f, 0.f, 0.f}, 0, 0, 0);
            }

            // ---- weight + exp (no-max softmax: |logit| <= ~0.2)
            int tb1 = blk * 32 + rg * 4;
            int tb2 = tb1 + 16;
            float p1[4], p2[4];
#pragma unroll
            for (int j = 0; j < 4; ++j) {
                p1[j] = exp2f(s1[j] * (fabsf(sf - (float)(tb1 + j)) * csw2));
                p2[j] = exp2f(s2[j] * (fabsf(sf - (float)(tb2 + j)) * csw2));
            }
            if (blk == 5) {                       // only tile2 holds t >= SEQ
#pragma unroll
                for (int j = 0; j < 4; ++j)
                    if (tb2 + j >= SEQ) p2[j] = 0.f;
            }
            lrow += ((p1[0] + p1[1]) + (p1[2] + p1[3]))
                  + ((p2[0] + p2[1]) + (p2[2] + p2[3]));

            // ---- P fragments: cvt_pk pairs ARE the 16x16x16 B-operand
            uint2 u1, u2;
            u1.x = cvt_pk_bf16(p1[0], p1[1]);
            u1.y = cvt_pk_bf16(p1[2], p1[3]);
            u2.x = cvt_pk_bf16(p2[0], p2[1]);
            u2.y = cvt_pk_bf16(p2[2], p2[3]);
            bf16x4 pf1 = *reinterpret_cast<bf16x4*>(&u1);
            bf16x4 pf2 = *reinterpret_cast<bf16x4*>(&u2);

            // ---- PV: O^T[d][q] += V^T[d][t] * P^T[t][q], two 16-t tiles
            int tA = blk * 32 + rg * 4;
            bf16x4 v1lo = *reinterpret_cast<const bf16x4*>(&Vt[cl][tA]);
            bf16x4 v2lo = *reinterpret_cast<const bf16x4*>(&Vt[cl][tA + 16]);
            bf16x4 v1hi = *reinterpret_cast<const bf16x4*>(&Vt[cl + 16][tA]);
            bf16x4 v2hi = *reinterpret_cast<const bf16x4*>(&Vt[cl + 16][tA + 16]);
            olo = mfma16x16x16(v1lo, pf1, olo);
            olo = mfma16x16x16(v2lo, pf2, olo);
            ohi = mfma16x16x16(v1hi, pf1, ohi);
            ohi = mfma16x16x16(v2hi, pf2, ohi);
        }

        // ---- row sum: q=cl lane-local; reduce over the 4 rg groups
        lrow += __shfl_xor(lrow, 16);
        lrow += __shfl_xor(lrow, 32);

        // ---- store: lane owns O[q=sq][d = rg*4..+3 and +16], b64 each
        if (sq < SEQ) {
            float rl = 1.0f / lrow;
            __hip_bfloat16* op = &O[base + (size_t)sq * EMB];
            uint2 wlo, whi;
            wlo.x = cvt_pk_bf16(olo[0] * rl, olo[1] * rl);
            wlo.y = cvt_pk_bf16(olo[2] * rl, olo[3] * rl);
            whi.x = cvt_pk_bf16(ohi[0] * rl, ohi[1] * rl);
            whi.y = cvt_pk_bf16(ohi[2] * rl, ohi[3] * rl);
            *reinterpret_cast<uint2*>(&op[rg * 4])      = wlo;
            *reinterpret_cast<uint2*>(&op[16 + rg * 4]) = whi;
        }
    }
}

// ---------------- row LayerNorm + PE: wave-per-row, 4 rows/block, bf16 io
__global__ __launch_bounds__(256) void ln_pe4_kernel(
    const __hip_bfloat16* __restrict__ X, const float* __restrict__ g,
    const float* __restrict__ bb, const float* __restrict__ pe,
    __hip_bfloat16* __restrict__ Xb, int M)
{
    int r = blockIdx.x * 4 + (threadIdx.x >> 6);
    if (r >= M) return;
    int lane = threadIdx.x & 63;
    int s = r % SEQ;
    int c0 = lane * 4;

    uint2 raw = *reinterpret_cast<const uint2*>(&X[(size_t)r * EMB + c0]);
    float v[4];
    v[0] = __uint_as_float((raw.x & 0xffffu) << 16);
    v[1] = __uint_as_float(raw.x & 0xffff0000u);
    v[2] = __uint_as_float((raw.y & 0xffffu) << 16);
    v[3] = __uint_as_float(raw.y & 0xffff0000u);

    float sum = v[0] + v[1] + v[2] + v[3];
    float sq  = v[0]*v[0] + v[1]*v[1] + v[2]*v[2] + v[3]*v[3];
#pragma unroll
    for (int off = 32; off > 0; off >>= 1) {
        sum += __shfl_xor(sum, off);
        sq  += __shfl_xor(sq,  off);
    }
    float mu  = sum * (1.0f / EMB);
    float var = sq * (1.0f / EMB) - mu * mu;
    float is  = rsqrtf(var + EPSV);

    float4 gv = *reinterpret_cast<const float4*>(&g[c0]);
    float4 bv = *reinterpret_cast<const float4*>(&bb[c0]);
    float4 pv = *reinterpret_cast<const float4*>(&pe[s * EMB + c0]);
    float y0 = (v[0] - mu) * is * gv.x + bv.x + pv.x;
    float y1 = (v[1] - mu) * is * gv.y + bv.y + pv.y;
    float y2 = (v[2] - mu) * is * gv.z + bv.z + pv.z;
    float y3 = (v[3] - mu) * is * gv.w + bv.w + pv.w;

    uint2 o;
    o.x = cvt_pk_bf16(y0, y1);
    o.y = cvt_pk_bf16(y2, y3);
    *reinterpret_cast<uint2*>(&Xb[(size_t)r * EMB + c0]) = o;
}

// ------- fused: LN(lnA2) -> LN(ln2) -> mean-pool over SEQ -> FC[10], 16 waves
__global__ __launch_bounds__(1024) void lnfc_kernel(
    const __hip_bfloat16* __restrict__ X,
    const float* __restrict__ g1, const float* __restrict__ b1,
    const float* __restrict__ g2, const float* __restrict__ b2,
    const float* __restrict__ ow, const float* __restrict__ ob,
    float* __restrict__ out)
{
    int b    = blockIdx.x;
    int tid  = threadIdx.x;
    int wave = tid >> 6, lane = tid & 63;

    float g1v[4], b1v[4], g2v[4], b2v[4], pooled[4];
#pragma unroll
    for (int j = 0; j < 4; ++j) {
        int c = lane + 64 * j;
        g1v[j] = g1[c]; b1v[j] = b1[c];
        g2v[j] = g2[c]; b2v[j] = b2[c];
        pooled[j] = 0.f;
    }

    for (int s = wave; s < SEQ; s += 16) {
        const __hip_bfloat16* row = &X[((size_t)b * SEQ + s) * EMB];
        float v[4];
#pragma unroll
        for (int j = 0; j < 4; ++j) v[j] = __bfloat162float(row[lane + 64 * j]);

        float sum = v[0] + v[1] + v[2] + v[3];
        float sq  = v[0]*v[0] + v[1]*v[1] + v[2]*v[2] + v[3]*v[3];
#pragma unroll
        for (int off = 32; off > 0; off >>= 1) {
            sum += __shfl_xor(sum, off);
            sq  += __shfl_xor(sq,  off);
        }
        float mu  = sum * (1.0f / EMB);
        float var = sq * (1.0f / EMB) - mu * mu;
        float is  = rsqrtf(var + EPSV);
        float y[4];
#pragma unroll
        for (int j = 0; j < 4; ++j) y[j] = (v[j] - mu) * is * g1v[j] + b1v[j];

        sum = y[0] + y[1] + y[2] + y[3];
        sq  = y[0]*y[0] + y[1]*y[1] + y[2]*y[2] + y[3]*y[3];
#pragma unroll
        for (int off = 32; off > 0; off >>= 1) {
            sum += __shfl_xor(sum, off);
            sq  += __shfl_xor(sq,  off);
        }
        mu  = sum * (1.0f / EMB);
        var = sq * (1.0f / EMB) - mu * mu;
        is  = rsqrtf(var + EPSV);
#pragma unroll
        for (int j = 0; j < 4; ++j) pooled[j] += (y[j] - mu) * is * g2v[j] + b2v[j];
    }

    __shared__ float pp[16][EMB];
#pragma unroll
    for (int j = 0; j < 4; ++j) pp[wave][lane + 64 * j] = pooled[j];
    __syncthreads();
    __shared__ float pool[EMB];
    if (tid < EMB) {
        float pl = 0.f;
#pragma unroll
        for (int w = 0; w < 16; ++w) pl += pp[w][tid];
        pool[tid] = pl * (1.0f / (float)SEQ);
    }
    __syncthreads();
    if (tid < 10) {
        float o = ob[tid];
        for (int k = 0; k < EMB; ++k) o += pool[k] * ow[tid * EMB + k];
        out[b * 10 + tid] = o;
    }
}

// ---------------------------------------------------------------- launch
extern "C" void kernel_launch(void* const* d_in, const int* in_sizes, int n_in,
                              void* d_out, int out_size, void* d_ws, size_t ws_size,
                              hipStream_t stream)
{
    const float* x      = (const float*)d_in[0];
    const float* conv_w = (const float*)d_in[1];
    const float* conv_b = (const float*)d_in[2];
    const float* bn_g   = (const float*)d_in[3];
    const float* bn_b   = (const float*)d_in[4];
    const float* bn_m   = (const float*)d_in[5];
    const float* bn_v   = (const float*)d_in[6];
    const float* wq1    = (const float*)d_in[7];
    const float* wk1    = (const float*)d_in[8];
    const float* wv1    = (const float*)d_in[9];
    const float* lnA1_g = (const float*)d_in[10];
    const float* lnA1_b = (const float*)d_in[11];
    const float* wq2    = (const float*)d_in[12];
    const float* wk2    = (const float*)d_in[13];
    const float* wv2    = (const float*)d_in[14];
    const float* lnA2_g = (const float*)d_in[15];
    const float* lnA2_b = (const float*)d_in[16];
    const float* ln2_g  = (const float*)d_in[17];
    const float* ln2_b  = (const float*)d_in[18];
    const float* out_w  = (const float*)d_in[19];
    const float* out_b  = (const float*)d_in[20];
    float* out = (float*)d_out;

    const size_t peN = (size_t)SEQ * EMB;
    const size_t wN  = (size_t)EMB * EMB;
    const size_t foldN = 8 * EMB + EMB;           // wt[8][256] + bp[256]

    int chunk = B_TOT;
    while (chunk > 1) {
        size_t M    = (size_t)chunk * SEQ;
        size_t Mpad = (M + 127) / 128 * 128;
        size_t need = (peN + foldN) * 4 + 6 * wN * 2 + (Mpad + 4 * M) * EMB * 2;
        if (need <= ws_size) break;
        chunk >>= 1;
    }
    size_t M    = (size_t)chunk * SEQ;
    size_t Mpad = (M + 127) / 128 * 128;

    float*          pe = (float*)d_ws;
    float*          wt = pe + peN;
    float*          bp = wt + 8 * EMB;
    __hip_bfloat16* Wb = (__hip_bfloat16*)(bp + EMB);
    __hip_bfloat16* Xb = Wb + 6 * wN;
    __hip_bfloat16* Ob = Xb + Mpad * EMB;
    __hip_bfloat16* Qb = Ob + M * EMB;
    __hip_bfloat16* Kb = Qb + M * EMB;
    __hip_bfloat16* Vb = Kb + M * EMB;

    pe_kernel<<<(SEQ * EMB + 255) / 256, 256, 0, stream>>>(pe);
    fold_conv_kernel<<<1, 256, 0, stream>>>(conv_w, conv_b, bn_g, bn_b, bn_m, bn_v, wt, bp);
    {
        dim3 cg((unsigned)(wN / 1024), 6);
        cvt6_kernel<<<cg, 256, 0, stream>>>(wq1, wk1, wv1, wq2, wk2, wv2, Wb, (int)wN);
    }

    for (int b0 = 0; b0 < B_TOT; b0 += chunk) {
        int Bc = chunk;
        int Mi = Bc * SEQ;
        unsigned nwg = 6u * (unsigned)(Mpad / 128);

        embed_kernel<<<(Mi + 15) / 16, 256, 0, stream>>>(
            x + (size_t)b0 * LIN, wt, bp, pe, Xb, Mi);

        // --- attention block 1 ---
        gemm_qkv_mfma<<<nwg, 256, 0, stream>>>(Xb, Wb, Qb, Kb, Vb, Mi);
        attn_mfma_kernel<<<Bc * HEADS, 256, 0, stream>>>(Qb, Kb, Vb, Ob);
        ln_pe4_kernel<<<(Mi + 3) / 4, 256, 0, stream>>>(Ob, lnA1_g, lnA1_b, pe, Xb, Mi);

        // --- attention block 2 ---
        gemm_qkv_mfma<<<nwg, 256, 0, stream>>>(Xb, Wb + 3 * wN, Qb, Kb, Vb, Mi);
        attn_mfma_kernel<<<Bc * HEADS, 256, 0, stream>>>(Qb, Kb, Vb, Ob);
        lnfc_kernel<<<Bc, 1024, 0, stream>>>(Ob, lnA2_g, lnA2_b, ln2_g, ln2_b,
                                             out_w, out_b, out + (size_t)b0 * 10);
    }
}